// Round 16
// baseline (184.000 us; speedup 1.0000x reference)
//
#include <hip/hip_runtime.h>
#include <hip/hip_bf16.h>
#include <hip/hip_fp16.h>

#define NNODES 20000
#define MPAD   20480              // 160 * 128 row-tiles, no M-guards anywhere
#define NEDGES 320000
#define DIM    128
#define NH     4
#define ETOT   (NEDGES + NNODES)
#define LN_EPS 1e-5f

typedef unsigned char  u8;
typedef unsigned short u16;
typedef unsigned int   u32;

typedef _Float16    f16x2 __attribute__((ext_vector_type(2)));
typedef _Float16    f16x8 __attribute__((ext_vector_type(8)));
typedef float       f32x2 __attribute__((ext_vector_type(2)));
typedef float       f32x4 __attribute__((ext_vector_type(4)));

__device__ inline u16 f2h(float f) {
    _Float16 h = (_Float16)f;
    union { _Float16 h; u16 u; } v; v.h = h; return v.u;
}
__device__ inline _Float16 bits2h(u16 b) {
    union { u16 u; _Float16 h; } v; v.u = b; return v.h;
}
__device__ inline f16x2 u2h2(u32 u) { union { u32 u; f16x2 h; } v; v.u = u; return v.h; }
__device__ inline u32 h22u(f16x2 h) { union { f16x2 h; u32 u; } v; v.h = h; return v.u; }
__device__ inline f16x2 habs2(f16x2 h) { return u2h2(h22u(h) & 0x7FFF7FFFu); }

// DPP row_ror rotate (16-lane row), pure-VALU cross-lane
#define DPP_ROR(x, ctrl) ({ union {float f; int i;} _a, _b; _a.f=(x); \
    _b.i = __builtin_amdgcn_update_dpp(0, _a.i, (ctrl), 0xF, 0xF, true); _b.f; })
__device__ inline float rowsum16(float x) {
    x += DPP_ROR(x, 0x121); x += DPP_ROR(x, 0x122);
    x += DPP_ROR(x, 0x124); x += DPP_ROR(x, 0x128);
    return x;
}
__device__ inline float rowmax16(float x) {
    x = fmaxf(x, DPP_ROR(x, 0x121)); x = fmaxf(x, DPP_ROR(x, 0x122));
    x = fmaxf(x, DPP_ROR(x, 0x124)); x = fmaxf(x, DPP_ROR(x, 0x128));
    return x;
}

// async global->LDS, 16B per lane, linear LDS dest
#define GLDS16(g, l) __builtin_amdgcn_global_load_lds(                         \
    (const __attribute__((address_space(1))) void*)(g),                        \
    (__attribute__((address_space(3))) void*)(l), 16, 0, 0)

#define LOG2E 1.44269504f

// ---- fused prep: deg init + x->f16 + W->Bt via LDS transpose ----

__global__ __launch_bounds__(256) void k_prep(const float* __restrict__ x, u16* __restrict__ xb,
                       const float* __restrict__ Wl1, const float* __restrict__ Wr1,
                       u16* __restrict__ Bt1,
                       const float* __restrict__ Wl2, const float* __restrict__ Wr2,
                       u16* __restrict__ Bt2,
                       int* __restrict__ deg) {
    const int b = blockIdx.x, t = threadIdx.x;
    const int gid = b * 256 + t;
    if (gid < NNODES) deg[gid] = 1;   // self-loop

    for (int j = gid; j < NNODES * 32; j += 256 * 256) {
        float4 v = ((const float4*)x)[j];
        ushort4 o;
        o.x = f2h(v.x); o.y = f2h(v.y); o.z = f2h(v.z); o.w = f2h(v.w);
        ((ushort4*)xb)[j] = o;
    }

    {
        const int m    = b >> 6;
        const int tile = b & 63;
        const int kt   = tile >> 4;
        const int nt   = tile & 15;
        const float* W = (m == 0) ? Wl1 : (m == 1) ? Wr1 : (m == 2) ? Wl2 : Wr2;
        u16* Bt        = (m < 2) ? Bt1 : Bt2;
        const int nbase = (m & 1) * 512 + nt * 32;

        __shared__ float lds[32][33];
        const int tx = t & 31, ty = t >> 5;
#pragma unroll
        for (int i = 0; i < 4; ++i) {
            int k = kt * 32 + ty + i * 8;
            lds[ty + i * 8][tx] = W[k * 512 + nt * 32 + tx];
        }
        __syncthreads();
#pragma unroll
        for (int i = 0; i < 4; ++i) {
            int nrow = nbase + ty + i * 8;
            Bt[nrow * 128 + kt * 32 + tx] = f2h(lds[tx][ty + i * 8]);
        }
    }
}

// ---------------- CSR build ----------------

__global__ void k_hist(const int* __restrict__ dst, int* __restrict__ deg) {
    int i = blockIdx.x * blockDim.x + threadIdx.x;
    if (i < NEDGES) atomicAdd(&deg[dst[i]], 1);
}

__global__ __launch_bounds__(1024) void k_scan(const int* __restrict__ deg,
                                               int* __restrict__ row,
                                               int* __restrict__ cur) {
    __shared__ int part[1024];
    const int CH = 20;
    int t = threadIdx.x;
    int base = t * CH;
    int s = 0;
    int d[20];
    if (base < NNODES) {
#pragma unroll
        for (int q = 0; q < 5; ++q) {
            int4 v = ((const int4*)(deg + base))[q];
            d[q*4+0] = v.x; d[q*4+1] = v.y; d[q*4+2] = v.z; d[q*4+3] = v.w;
            s += v.x + v.y + v.z + v.w;
        }
    }
    part[t] = s;
    __syncthreads();
    for (int off = 1; off < 1024; off <<= 1) {
        int v = (t >= off) ? part[t - off] : 0;
        __syncthreads();
        part[t] += v;
        __syncthreads();
    }
    if (base < NNODES) {
        int run = (t == 0) ? 0 : part[t - 1];
#pragma unroll
        for (int i = 0; i < CH; i++) {
            row[base + i] = run; cur[base + i] = run; run += d[i];
        }
    }
    if (t == 1023) row[NNODES] = part[1023];
}

__global__ void k_scatter(const int* __restrict__ src, const int* __restrict__ dst,
                          int* __restrict__ col, int* __restrict__ cur) {
    int i = blockIdx.x * blockDim.x + threadIdx.x;
    if (i < NEDGES) {
        int d = dst[i];
        int pos = atomicAdd(&cur[d], 1);
        col[pos] = src[i];
    } else if (i < ETOT) {
        int n = i - NEDGES;
        int pos = atomicAdd(&cur[n], 1);
        col[pos] = n;
    }
}

// ------------- fp16 MFMA GEMM + fused int8 quant + fused att-dot precompute -------------
// Dl6 = 0.6*log2e*dot(xl,att) packed with scale; Dr6 = 0.6*log2e*dot(xr,att).

__global__ __launch_bounds__(256, 2) void k_gemm_f16(const u16* __restrict__ A,
                                                     const u16* __restrict__ Bt,
                                                     const float* __restrict__ att,
                                                     u8*  __restrict__ XLq,
                                                     u32* __restrict__ sclD,
                                                     u16* __restrict__ Dr6,
                                                     u16* __restrict__ XR) {
    __shared__ u16 smA[128 * 128];
    __shared__ u16 smB[128 * 128];
    const int L   = blockIdx.x;
    const int xcd = L & 7;
    const int w9  = L >> 3;
    const int bm  = (xcd * 20 + (w9 >> 3)) * 128;
    const int bn  = (w9 & 7) * 128;
    const int t  = threadIdx.x;
    const int w  = t >> 6;
    const int l  = t & 63;

    {
        char* smAb = (char*)smA;
        char* smBb = (char*)smB;
#pragma unroll
        for (int p = 0; p < 8; ++p) {
            int rbase = w * 32 + p * 4;
            int row   = rbase + (l >> 4);
            int j     = (l & 15) ^ (row & 7);
            const u16* ga = A  + (size_t)(bm + row) * 128 + j * 8;
            const u16* gb = Bt + (size_t)(bn + row) * 128 + j * 8;
            GLDS16(ga, smAb + rbase * 256);
            GLDS16(gb, smBb + rbase * 256);
        }
    }
    __syncthreads();

    const int wr  = (w >> 1) * 64;
    const int wc  = (w & 1) * 64;
    const int lr  = l & 15;
    const int lkb = (l >> 4) * 16;

    f32x4 acc[4][4] = {};

#pragma unroll
    for (int ks = 0; ks < 4; ++ks) {
        f16x8 af[4], bfr[4];
#pragma unroll
        for (int i = 0; i < 4; ++i) {
            int ra = wr + i * 16 + lr;
            af[i]  = *(const f16x8*)((const char*)smA +
                        ((ra * 256 + ks * 64 + lkb) ^ ((ra & 7) << 4)));
            int rb = wc + i * 16 + lr;
            bfr[i] = *(const f16x8*)((const char*)smB +
                        ((rb * 256 + ks * 64 + lkb) ^ ((rb & 7) << 4)));
        }
#pragma unroll
        for (int mi = 0; mi < 4; ++mi)
#pragma unroll
            for (int ni = 0; ni < 4; ++ni)
                acc[mi][ni] = __builtin_amdgcn_mfma_f32_16x16x32_f16(
                    bfr[ni], af[mi], acc[mi][ni], 0, 0, 0);
    }

    __syncthreads();
    u16* smC = smA;
    {
        const int n4 = (l >> 4) * 4;
#pragma unroll
        for (int mi = 0; mi < 4; ++mi) {
            int m = wr + mi * 16 + lr;
#pragma unroll
            for (int ni = 0; ni < 4; ++ni) {
                int n = wc + ni * 16 + n4;
                f32x4 v = acc[mi][ni];
                ushort4 o;
                o.x = f2h(v[0]); o.y = f2h(v[1]); o.z = f2h(v[2]); o.w = f2h(v[3]);
                *(ushort4*)((char*)smC + (m * 256 + ((n * 2) ^ ((m & 7) << 4)))) = o;
            }
        }
    }
    __syncthreads();

    const int lr16 = l & 15;
    const int rg   = l >> 4;
    const int head = (bn < 512) ? (bn >> 7) : ((bn >> 7) - 4);
    const float* ap = att + head * 128 + lr16 * 8;
    float4 aa0 = *(const float4*)(ap);
    float4 aa1 = *(const float4*)(ap + 4);
    const float av[8] = {aa0.x, aa0.y, aa0.z, aa0.w, aa1.x, aa1.y, aa1.z, aa1.w};

    if (bn < 512) {
#pragma unroll
        for (int p = 0; p < 8; ++p) {
            int r = w * 32 + p * 4 + rg;
            uint4 vv = *(const uint4*)((const char*)smC +
                        (r * 256 + ((lr16 * 16) ^ ((r & 7) << 4))));
            f32x2 c0 = __builtin_convertvector(u2h2(vv.x), f32x2);
            f32x2 c1 = __builtin_convertvector(u2h2(vv.y), f32x2);
            f32x2 c2 = __builtin_convertvector(u2h2(vv.z), f32x2);
            f32x2 c3 = __builtin_convertvector(u2h2(vv.w), f32x2);
            float f[8] = {c0[0],c0[1],c1[0],c1[1],c2[0],c2[1],c3[0],c3[1]};
            float m = 0.f, d = 0.f;
#pragma unroll
            for (int k = 0; k < 8; ++k) { m = fmaxf(m, fabsf(f[k])); d += f[k] * av[k]; }
            m = rowmax16(m);
            d = rowsum16(d);
            float inv = (m > 0.f) ? (127.f / m) : 0.f;
            int q[8];
#pragma unroll
            for (int k = 0; k < 8; ++k) {
                int qi = (int)__builtin_rintf(f[k] * inv);
                q[k] = qi > 127 ? 127 : (qi < -127 ? -127 : qi);
            }
            u32 lo = (q[0]&255) | ((q[1]&255)<<8) | ((q[2]&255)<<16) | ((q[3]&255)<<24);
            u32 hi = (q[4]&255) | ((q[5]&255)<<8) | ((q[6]&255)<<16) | ((q[7]&255)<<24);
            uint2 pk; pk.x = lo; pk.y = hi;
            *(uint2*)(XLq + (size_t)(bm + r) * 512 + head * 128 + lr16 * 8) = pk;
            if (lr16 == 0)
                sclD[(bm + r) * 4 + head] =
                    (u32)f2h(m * (1.f / 127.f)) | ((u32)f2h(0.6f * LOG2E * d) << 16);
        }
    } else {
#pragma unroll
        for (int p = 0; p < 8; ++p) {
            int r = w * 32 + p * 4 + rg;
            uint4 vv = *(const uint4*)((const char*)smC +
                        (r * 256 + ((lr16 * 16) ^ ((r & 7) << 4))));
            f32x2 c0 = __builtin_convertvector(u2h2(vv.x), f32x2);
            f32x2 c1 = __builtin_convertvector(u2h2(vv.y), f32x2);
            f32x2 c2 = __builtin_convertvector(u2h2(vv.z), f32x2);
            f32x2 c3 = __builtin_convertvector(u2h2(vv.w), f32x2);
            float f[8] = {c0[0],c0[1],c1[0],c1[1],c2[0],c2[1],c3[0],c3[1]};
            float d = 0.f;
#pragma unroll
            for (int k = 0; k < 8; ++k) d += f[k] * av[k];
            d = rowsum16(d);
            if (lr16 == 0) Dr6[(bm + r) * 4 + head] = f2h(0.6f * LOG2E * d);
        }
        int r  = t >> 4;
        int cb = (t & 15) * 16;
        u16* base = XR + (bn - 512);
#pragma unroll
        for (int p = 0; p < 8; ++p) {
            int row = p * 16 + r;
            uint4 v = *(const uint4*)((const char*)smC +
                        (row * 256 + (cb ^ ((row & 7) << 4))));
            *(uint4*)(base + (size_t)(bm + row) * 512 + (cb >> 1)) = v;
        }
    }
}

// ------------- fused GATv2 attention + head-mean + bias + LN + residual -------------
// e' = log2e*score; p = exp2(e'). 4-edge unroll for latency hiding.

__global__ __launch_bounds__(256) void k_attn(const u8*  __restrict__ XLq,
                                              const u32* __restrict__ sclD,
                                              const u16* __restrict__ Dr6,
                                              const u16* __restrict__ XR,
                                              const float* __restrict__ att,
                                              const float* __restrict__ bias,
                                              const float* __restrict__ gamma,
                                              const float* __restrict__ beta,
                                              const int* __restrict__ row,
                                              const int* __restrict__ col,
                                              const float* __restrict__ res,
                                              float* __restrict__ out,
                                              u16* __restrict__ out_h,
                                              int relu_flag) {
    const int wid = __builtin_amdgcn_readfirstlane(threadIdx.x >> 6);
    const int n   = blockIdx.x * 4 + wid;          // grid = NNODES/4 exactly
    const int l   = threadIdx.x & 63;
    const int h   = l >> 4;
    const int e   = l & 15;

    const f16x2 M1152 = {(_Float16)(-1152.f), (_Float16)(-1152.f)};
    const u32 K64 = 0x64646464u;

    const int lane_off = h * 128 + e * 8;

    uint4 xru = *(const uint4*)(XR + (size_t)n * 512 + lane_off);
    f16x2 xr0 = u2h2(xru.x), xr1 = u2h2(xru.y), xr2 = u2h2(xru.z), xr3 = u2h2(xru.w);

    // 0.4*log2e*att in f16 pairs
    const float* ap = att + lane_off;
    float4 af0 = *(const float4*)(ap);
    float4 af1 = *(const float4*)(ap + 4);
    const float AS = 0.4f * LOG2E;
    f16x2 at0 = {(_Float16)(AS*af0.x), (_Float16)(AS*af0.y)};
    f16x2 at1 = {(_Float16)(AS*af0.z), (_Float16)(AS*af0.w)};
    f16x2 at2 = {(_Float16)(AS*af1.x), (_Float16)(AS*af1.y)};
    f16x2 at3 = {(_Float16)(AS*af1.z), (_Float16)(AS*af1.w)};

    const float dr6n = (float)bits2h(Dr6[n * 4 + h]);   // 0.6*log2e*dot(xr_n, att_h)

    f16x2 acch[4] = {};
    float ssum = 0.f;

    const int beg = row[n], end = row[n + 1];

#define EDGE_SCORE(QA, QB, QC, QD, SC, EO)                                   \
    {                                                                        \
        f16x2 v0 = QA * SC + xr0, v1 = QB * SC + xr1;                        \
        f16x2 v2 = QC * SC + xr2, v3 = QD * SC + xr3;                        \
        EO = __builtin_amdgcn_fdot2(habs2(v0), at0, 0.f, false);             \
        EO = __builtin_amdgcn_fdot2(habs2(v1), at1, EO, false);              \
        EO = __builtin_amdgcn_fdot2(habs2(v2), at2, EO, false);              \
        EO = __builtin_amdgcn_fdot2(habs2(v3), at3, EO, false);              \
    }

    for (int i = beg; i < end; i += 4) {
        int s0 = col[i];
        bool h1 = (i + 1 < end), h2 = (i + 2 < end), h3 = (i + 3 < end);
        int s1 = h1 ? col[i + 1] : s0;
        int s2 = h2 ? col[i + 2] : s0;
        int s3 = h3 ? col[i + 3] : s0;

        uint2 a0 = *(const uint2*)(XLq + (size_t)s0 * 512 + lane_off);
        uint2 a1 = *(const uint2*)(XLq + (size_t)s1 * 512 + lane_off);
        uint2 a2 = *(const uint2*)(XLq + (size_t)s2 * 512 + lane_off);
        uint2 a3 = *(const uint2*)(XLq + (size_t)s3 * 512 + lane_off);
        u32 sd0 = sclD[s0 * 4 + h];
        u32 sd1 = sclD[s1 * 4 + h];
        u32 sd2 = sclD[s2 * 4 + h];
        u32 sd3 = sclD[s3 * 4 + h];
        _Float16 sh0 = bits2h((u16)sd0), sh1 = bits2h((u16)sd1);
        _Float16 sh2 = bits2h((u16)sd2), sh3 = bits2h((u16)sd3);
        float d60 = dr6n + (float)bits2h((u16)(sd0 >> 16));
        float d61 = dr6n + (float)bits2h((u16)(sd1 >> 16));
        float d62 = dr6n + (float)bits2h((u16)(sd2 >> 16));
        float d63 = dr6n + (float)bits2h((u16)(sd3 >> 16));
        f16x2 sc0 = {sh0, sh0}, sc1 = {sh1, sh1};
        f16x2 sc2 = {sh2, sh2}, sc3 = {sh3, sh3};

        // magic decode int8 -> f16 (exact)
        u32 w00 = a0.x ^ 0x80808080u, w01 = a0.y ^ 0x80808080u;
        u32 w10 = a1.x ^ 0x80808080u, w11 = a1.y ^ 0x80808080u;
        u32 w20 = a2.x ^ 0x80808080u, w21 = a2.y ^ 0x80808080u;
        u32 w30 = a3.x ^ 0x80808080u, w31 = a3.y ^ 0x80808080u;
        f16x2 q00 = u2h2(__builtin_amdgcn_perm(K64, w00, 0x04010400u)) + M1152;
        f16x2 q01 = u2h2(__builtin_amdgcn_perm(K64, w00, 0x04030402u)) + M1152;
        f16x2 q02 = u2h2(__builtin_amdgcn_perm(K64, w01, 0x04010400u)) + M1152;
        f16x2 q03 = u2h2(__builtin_amdgcn_perm(K64, w01, 0x04030402u)) + M1152;
        f16x2 q10 = u2h2(__builtin_amdgcn_perm(K64, w10, 0x04010400u)) + M1152;
        f16x2 q11 = u2h2(__builtin_amdgcn_perm(K64, w10, 0x04030402u)) + M1152;
        f16x2 q12 = u2h2(__builtin_amdgcn_perm(K64, w11, 0x04010400u)) + M1152;
        f16x2 q13 = u2h2(__builtin_amdgcn_perm(K64, w11, 0x04030402u)) + M1152;
        f16x2 q20 = u2h2(__builtin_amdgcn_perm(K64, w20, 0x04010400u)) + M1152;
        f16x2 q21 = u2h2(__builtin_amdgcn_perm(K64, w20, 0x04030402u)) + M1152;
        f16x2 q22 = u2h2(__builtin_amdgcn_perm(K64, w21, 0x04010400u)) + M1152;
        f16x2 q23 = u2h2(__builtin_amdgcn_perm(K64, w21, 0x04030402u)) + M1152;
        f16x2 q30 = u2h2(__builtin_amdgcn_perm(K64, w30, 0x04010400u)) + M1152;
        f16x2 q31 = u2h2(__builtin_amdgcn_perm(K64, w30, 0x04030402u)) + M1152;
        f16x2 q32 = u2h2(__builtin_amdgcn_perm(K64, w31, 0x04010400u)) + M1152;
        f16x2 q33 = u2h2(__builtin_amdgcn_perm(K64, w31, 0x04030402u)) + M1152;

        float e0, e1, e2, e3;
        EDGE_SCORE(q00, q01, q02, q03, sc0, e0);
        EDGE_SCORE(q10, q11, q12, q13, sc1, e1);
        EDGE_SCORE(q20, q21, q22, q23, sc2, e2);
        EDGE_SCORE(q30, q31, q32, q33, sc3, e3);

        // 16-lane row reduce via DPP, 4 chains interleaved
        e0 += DPP_ROR(e0, 0x121); e1 += DPP_ROR(e1, 0x121);
        e2 += DPP_ROR(e2, 0x121); e3 += DPP_ROR(e3, 0x121);
        e0 += DPP_ROR(e0, 0x122); e1 += DPP_ROR(e1, 0x122);
        e2 += DPP_ROR(e2, 0x122); e3 += DPP_ROR(e3, 0x122);
        e0 += DPP_ROR(e0, 0x124); e1 += DPP_ROR(e1, 0x124);
        e2 += DPP_ROR(e2, 0x124); e3 += DPP_ROR(e3, 0x124);
        e0 += DPP_ROR(e0, 0x128); e1 += DPP_ROR(e1, 0x128);
        e2 += DPP_ROR(e2, 0x128); e3 += DPP_ROR(e3, 0x128);

        float p0 = exp2f(e0 + d60);
        float p1 = h1 ? exp2f(e1 + d61) : 0.f;
        float p2 = h2 ? exp2f(e2 + d62) : 0.f;
        float p3 = h3 ? exp2f(e3 + d63) : 0.f;
        ssum += (p0 + p1) + (p2 + p3);

        _Float16 w0s = (_Float16)(p0 * (float)sh0);
        _Float16 w1s = (_Float16)(p1 * (float)sh1);
        _Float16 w2s = (_Float16)(p2 * (float)sh2);
        _Float16 w3s = (_Float16)(p3 * (float)sh3);
        f16x2 pw0 = {w0s, w0s}, pw1 = {w1s, w1s};
        f16x2 pw2 = {w2s, w2s}, pw3 = {w3s, w3s};
        acch[0] = ((acch[0] + pw0 * q00) + pw1 * q10) + (pw2 * q20 + pw3 * q30);
        acch[1] = ((acch[1] + pw0 * q01) + pw1 * q11) + (pw2 * q21 + pw3 * q31);
        acch[2] = ((acch[2] + pw0 * q02) + pw1 * q12) + (pw2 * q22 + pw3 * q32);
        acch[3] = ((acch[3] + pw0 * q03) + pw1 * q13) + (pw2 * q23 + pw3 * q33);
    }
#undef EDGE_SCORE

    float acc[8];
    {
        f32x2 c;
        c = __builtin_convertvector(acch[0], f32x2); acc[0] = c[0]; acc[1] = c[1];
        c = __builtin_convertvector(acch[1], f32x2); acc[2] = c[0]; acc[3] = c[1];
        c = __builtin_convertvector(acch[2], f32x2); acc[4] = c[0]; acc[5] = c[1];
        c = __builtin_convertvector(acch[3], f32x2); acc[6] = c[0]; acc[7] = c[1];
    }
    float inv = 1.f / (ssum + 1e-16f);
#pragma unroll
    for (int jj = 0; jj < 8; ++jj) acc[jj] *= inv;
#pragma unroll
    for (int jj = 0; jj < 8; ++jj) acc[jj] += __shfl_xor(acc[jj], 16, 64);
#pragma unroll
    for (int jj = 0; jj < 8; ++jj) acc[jj] += __shfl_xor(acc[jj], 32, 64);

    if (h == 0) {
        const int dd = e * 8;
        float4 b40 = *(const float4*)(bias + dd);
        float4 b41 = *(const float4*)(bias + dd + 4);
        float y[8];
        y[0] = acc[0]*0.25f + b40.x; y[1] = acc[1]*0.25f + b40.y;
        y[2] = acc[2]*0.25f + b40.z; y[3] = acc[3]*0.25f + b40.w;
        y[4] = acc[4]*0.25f + b41.x; y[5] = acc[5]*0.25f + b41.y;
        y[6] = acc[6]*0.25f + b41.z; y[7] = acc[7]*0.25f + b41.w;

        float s1 = 0.f, s2 = 0.f;
#pragma unroll
        for (int jj = 0; jj < 8; ++jj) { s1 += y[jj]; s2 += y[jj]*y[jj]; }
#pragma unroll
        for (int m = 1; m < 16; m <<= 1) {
            s1 += __shfl_xor(s1, m, 64);
            s2 += __shfl_xor(s2, m, 64);
        }
        float mu = s1 * (1.f / 128.f);
        float var = s2 * (1.f / 128.f) - mu * mu;
        float rstd = rsqrtf(var + LN_EPS);

        float4 g40 = *(const float4*)(gamma + dd);
        float4 g41 = *(const float4*)(gamma + dd + 4);
        float4 e40 = *(const float4*)(beta + dd);
        float4 e41 = *(const float4*)(beta + dd + 4);
        float4 r40 = *(const float4*)(res + (size_t)n * 128 + dd);
        float4 r41 = *(const float4*)(res + (size_t)n * 128 + dd + 4);
        float g[8] = {g40.x,g40.y,g40.z,g40.w,g41.x,g41.y,g41.z,g41.w};
        float be[8] = {e40.x,e40.y,e40.z,e40.w,e41.x,e41.y,e41.z,e41.w};
        float r[8] = {r40.x,r40.y,r40.z,r40.w,r41.x,r41.y,r41.z,r41.w};
#pragma unroll
        for (int jj = 0; jj < 8; ++jj) {
            y[jj] = (y[jj] - mu) * rstd * g[jj] + be[jj] + r[jj];
            if (relu_flag) y[jj] = fmaxf(y[jj], 0.f);
        }
        float4 o0 = {y[0],y[1],y[2],y[3]};
        float4 o1 = {y[4],y[5],y[6],y[7]};
        *(float4*)(out + (size_t)n * 128 + dd)     = o0;
        *(float4*)(out + (size_t)n * 128 + dd + 4) = o1;
        if (out_h) {
            ushort4 oh0, oh1;
            oh0.x = f2h(y[0]); oh0.y = f2h(y[1]); oh0.z = f2h(y[2]); oh0.w = f2h(y[3]);
            oh1.x = f2h(y[4]); oh1.y = f2h(y[5]); oh1.z = f2h(y[6]); oh1.w = f2h(y[7]);
            *(ushort4*)(out_h + (size_t)n * 128 + dd)     = oh0;
            *(ushort4*)(out_h + (size_t)n * 128 + dd + 4) = oh1;
        }
    }
}

// ---------------- launch ----------------

extern "C" void kernel_launch(void* const* d_in, const int* in_sizes, int n_in,
                              void* d_out, int out_size, void* d_ws, size_t ws_size,
                              hipStream_t stream) {
    const float* x    = (const float*)d_in[0];
    const int*   src  = (const int*)d_in[1];
    const int*   dst  = (const int*)d_in[2];
    const float* Wl1  = (const float*)d_in[3];
    const float* Wr1  = (const float*)d_in[4];
    const float* att1 = (const float*)d_in[5];
    const float* b1   = (const float*)d_in[6];
    const float* g1   = (const float*)d_in[7];
    const float* be1  = (const float*)d_in[8];
    const float* Wl2  = (const float*)d_in[9];
    const float* Wr2  = (const float*)d_in[10];
    const float* att2 = (const float*)d_in[11];
    const float* b2   = (const float*)d_in[12];
    const float* g2   = (const float*)d_in[13];
    const float* be2  = (const float*)d_in[14];
    float* out = (float*)d_out;

    char* ws = (char*)d_ws;
    size_t off = 0;
    u8*    xlq  = (u8*)(ws + off);    off += (size_t)MPAD * 512;          // int8 XL
    u32*   scld = (u32*)(ws + off);   off += (size_t)MPAD * 4 * 4;        // packed scale+Dl6
    u16*   dr6  = (u16*)(ws + off);   off += (size_t)MPAD * 4 * 2;        // Dr6 f16
    u16*   xrb  = (u16*)(ws + off);   off += (size_t)MPAD * 512 * 2;      // f16 XR
    u16*   xb   = (u16*)(ws + off);   off += (size_t)MPAD * 128 * 2;      // f16 A input
    float* hbuf = (float*)(ws + off); off += (size_t)NNODES * 128 * 4;
    u16*   Bt1  = (u16*)(ws + off);   off += (size_t)1024 * 128 * 2;
    u16*   Bt2  = (u16*)(ws + off);   off += (size_t)1024 * 128 * 2;
    int*   deg  = (int*)(ws + off);   off += (size_t)NNODES * 4;
    int*   rowp = (int*)(ws + off);   off += (size_t)(NNODES + 1) * 4;
    int*   cur  = (int*)(ws + off);   off += (size_t)NNODES * 4;
    int*   col  = (int*)(ws + off);   off += (size_t)ETOT * 4;

    k_prep<<<256, 256, 0, stream>>>(x, xb, Wl1, Wr1, Bt1, Wl2, Wr2, Bt2, deg);
    k_hist<<<(NEDGES + 255) / 256, 256, 0, stream>>>(dst, deg);
    k_scan<<<1, 1024, 0, stream>>>(deg, rowp, cur);
    k_scatter<<<(ETOT + 255) / 256, 256, 0, stream>>>(src, dst, col, cur);

    // layer 1
    k_gemm_f16<<<MPAD / 128 * 8, 256, 0, stream>>>(xb, Bt1, att1, xlq, scld, dr6, xrb);
    k_attn<<<NNODES / 4, 256, 0, stream>>>(xlq, scld, dr6, xrb, att1, b1, g1, be1,
                                           rowp, col, x, hbuf, xb, 1);
    // layer 2
    k_gemm_f16<<<MPAD / 128 * 8, 256, 0, stream>>>(xb, Bt2, att2, xlq, scld, dr6, xrb);
    k_attn<<<NNODES / 4, 256, 0, stream>>>(xlq, scld, dr6, xrb, att2, b2, g2, be2,
                                           rowp, col, hbuf, out, (u16*)nullptr, 0);
}

// Round 17
// 179.398 us; speedup vs baseline: 1.0256x; 1.0256x over previous
//
#include <hip/hip_runtime.h>
#include <hip/hip_bf16.h>
#include <hip/hip_fp16.h>

#define NNODES 20000
#define MPAD   20480              // 160 * 128 row-tiles, no M-guards anywhere
#define NEDGES 320000
#define DIM    128
#define NH     4
#define ETOT   (NEDGES + NNODES)
#define LN_EPS 1e-5f

typedef unsigned char  u8;
typedef unsigned short u16;
typedef unsigned int   u32;

typedef _Float16    f16x2 __attribute__((ext_vector_type(2)));
typedef _Float16    f16x8 __attribute__((ext_vector_type(8)));
typedef float       f32x2 __attribute__((ext_vector_type(2)));
typedef float       f32x4 __attribute__((ext_vector_type(4)));

__device__ inline u16 f2h(float f) {
    _Float16 h = (_Float16)f;
    union { _Float16 h; u16 u; } v; v.h = h; return v.u;
}
__device__ inline _Float16 bits2h(u16 b) {
    union { u16 u; _Float16 h; } v; v.u = b; return v.h;
}
__device__ inline f16x2 u2h2(u32 u) { union { u32 u; f16x2 h; } v; v.u = u; return v.h; }
__device__ inline u32 h22u(f16x2 h) { union { f16x2 h; u32 u; } v; v.h = h; return v.u; }
__device__ inline f16x2 habs2(f16x2 h) { return u2h2(h22u(h) & 0x7FFF7FFFu); }

// DPP row_ror rotate (16-lane row), pure-VALU cross-lane
#define DPP_ROR(x, ctrl) ({ union {float f; int i;} _a, _b; _a.f=(x); \
    _b.i = __builtin_amdgcn_update_dpp(0, _a.i, (ctrl), 0xF, 0xF, true); _b.f; })
__device__ inline float rowsum16(float x) {
    x += DPP_ROR(x, 0x121); x += DPP_ROR(x, 0x122);
    x += DPP_ROR(x, 0x124); x += DPP_ROR(x, 0x128);
    return x;
}
__device__ inline float rowmax16(float x) {
    x = fmaxf(x, DPP_ROR(x, 0x121)); x = fmaxf(x, DPP_ROR(x, 0x122));
    x = fmaxf(x, DPP_ROR(x, 0x124)); x = fmaxf(x, DPP_ROR(x, 0x128));
    return x;
}

// async global->LDS, 16B per lane, linear LDS dest
#define GLDS16(g, l) __builtin_amdgcn_global_load_lds(                         \
    (const __attribute__((address_space(1))) void*)(g),                        \
    (__attribute__((address_space(3))) void*)(l), 16, 0, 0)

#define LOG2E 1.44269504f

// ---- fused prep: deg init + x->f16 + W->Bt via LDS transpose ----

__global__ __launch_bounds__(256) void k_prep(const float* __restrict__ x, u16* __restrict__ xb,
                       const float* __restrict__ Wl1, const float* __restrict__ Wr1,
                       u16* __restrict__ Bt1,
                       const float* __restrict__ Wl2, const float* __restrict__ Wr2,
                       u16* __restrict__ Bt2,
                       int* __restrict__ deg) {
    const int b = blockIdx.x, t = threadIdx.x;
    const int gid = b * 256 + t;
    if (gid < NNODES) deg[gid] = 1;   // self-loop

    for (int j = gid; j < NNODES * 32; j += 256 * 256) {
        float4 v = ((const float4*)x)[j];
        ushort4 o;
        o.x = f2h(v.x); o.y = f2h(v.y); o.z = f2h(v.z); o.w = f2h(v.w);
        ((ushort4*)xb)[j] = o;
    }

    {
        const int m    = b >> 6;
        const int tile = b & 63;
        const int kt   = tile >> 4;
        const int nt   = tile & 15;
        const float* W = (m == 0) ? Wl1 : (m == 1) ? Wr1 : (m == 2) ? Wl2 : Wr2;
        u16* Bt        = (m < 2) ? Bt1 : Bt2;
        const int nbase = (m & 1) * 512 + nt * 32;

        __shared__ float lds[32][33];
        const int tx = t & 31, ty = t >> 5;
#pragma unroll
        for (int i = 0; i < 4; ++i) {
            int k = kt * 32 + ty + i * 8;
            lds[ty + i * 8][tx] = W[k * 512 + nt * 32 + tx];
        }
        __syncthreads();
#pragma unroll
        for (int i = 0; i < 4; ++i) {
            int nrow = nbase + ty + i * 8;
            Bt[nrow * 128 + kt * 32 + tx] = f2h(lds[tx][ty + i * 8]);
        }
    }
}

// ---------------- CSR build ----------------

__global__ void k_hist(const int* __restrict__ dst, int* __restrict__ deg) {
    int i = blockIdx.x * blockDim.x + threadIdx.x;
    if (i < NEDGES) atomicAdd(&deg[dst[i]], 1);
}

__global__ __launch_bounds__(1024) void k_scan(const int* __restrict__ deg,
                                               int* __restrict__ row,
                                               int* __restrict__ cur) {
    __shared__ int part[1024];
    const int CH = 20;
    int t = threadIdx.x;
    int base = t * CH;
    int s = 0;
    int d[20];
    if (base < NNODES) {
#pragma unroll
        for (int q = 0; q < 5; ++q) {
            int4 v = ((const int4*)(deg + base))[q];
            d[q*4+0] = v.x; d[q*4+1] = v.y; d[q*4+2] = v.z; d[q*4+3] = v.w;
            s += v.x + v.y + v.z + v.w;
        }
    }
    part[t] = s;
    __syncthreads();
    for (int off = 1; off < 1024; off <<= 1) {
        int v = (t >= off) ? part[t - off] : 0;
        __syncthreads();
        part[t] += v;
        __syncthreads();
    }
    if (base < NNODES) {
        int run = (t == 0) ? 0 : part[t - 1];
#pragma unroll
        for (int i = 0; i < CH; i++) {
            row[base + i] = run; cur[base + i] = run; run += d[i];
        }
    }
    if (t == 1023) row[NNODES] = part[1023];
}

__global__ void k_scatter(const int* __restrict__ src, const int* __restrict__ dst,
                          int* __restrict__ col, int* __restrict__ cur) {
    int i = blockIdx.x * blockDim.x + threadIdx.x;
    if (i < NEDGES) {
        int d = dst[i];
        int pos = atomicAdd(&cur[d], 1);
        col[pos] = src[i];
    } else if (i < ETOT) {
        int n = i - NEDGES;
        int pos = atomicAdd(&cur[n], 1);
        col[pos] = n;
    }
}

// ------------- fp16 MFMA GEMM + fused int8 quant + fused att-dot precompute -------------
// Dl6 = 0.6*log2e*dot(xl,att) packed with scale; Dr6 = 0.6*log2e*dot(xr,att).

__global__ __launch_bounds__(256, 2) void k_gemm_f16(const u16* __restrict__ A,
                                                     const u16* __restrict__ Bt,
                                                     const float* __restrict__ att,
                                                     u8*  __restrict__ XLq,
                                                     u32* __restrict__ sclD,
                                                     u16* __restrict__ Dr6,
                                                     u16* __restrict__ XR) {
    __shared__ u16 smA[128 * 128];
    __shared__ u16 smB[128 * 128];
    const int L   = blockIdx.x;
    const int xcd = L & 7;
    const int w9  = L >> 3;
    const int bm  = (xcd * 20 + (w9 >> 3)) * 128;
    const int bn  = (w9 & 7) * 128;
    const int t  = threadIdx.x;
    const int w  = t >> 6;
    const int l  = t & 63;

    {
        char* smAb = (char*)smA;
        char* smBb = (char*)smB;
#pragma unroll
        for (int p = 0; p < 8; ++p) {
            int rbase = w * 32 + p * 4;
            int row   = rbase + (l >> 4);
            int j     = (l & 15) ^ (row & 7);
            const u16* ga = A  + (size_t)(bm + row) * 128 + j * 8;
            const u16* gb = Bt + (size_t)(bn + row) * 128 + j * 8;
            GLDS16(ga, smAb + rbase * 256);
            GLDS16(gb, smBb + rbase * 256);
        }
    }
    __syncthreads();

    const int wr  = (w >> 1) * 64;
    const int wc  = (w & 1) * 64;
    const int lr  = l & 15;
    const int lkb = (l >> 4) * 16;

    f32x4 acc[4][4] = {};

#pragma unroll
    for (int ks = 0; ks < 4; ++ks) {
        f16x8 af[4], bfr[4];
#pragma unroll
        for (int i = 0; i < 4; ++i) {
            int ra = wr + i * 16 + lr;
            af[i]  = *(const f16x8*)((const char*)smA +
                        ((ra * 256 + ks * 64 + lkb) ^ ((ra & 7) << 4)));
            int rb = wc + i * 16 + lr;
            bfr[i] = *(const f16x8*)((const char*)smB +
                        ((rb * 256 + ks * 64 + lkb) ^ ((rb & 7) << 4)));
        }
#pragma unroll
        for (int mi = 0; mi < 4; ++mi)
#pragma unroll
            for (int ni = 0; ni < 4; ++ni)
                acc[mi][ni] = __builtin_amdgcn_mfma_f32_16x16x32_f16(
                    bfr[ni], af[mi], acc[mi][ni], 0, 0, 0);
    }

    __syncthreads();
    u16* smC = smA;
    {
        const int n4 = (l >> 4) * 4;
#pragma unroll
        for (int mi = 0; mi < 4; ++mi) {
            int m = wr + mi * 16 + lr;
#pragma unroll
            for (int ni = 0; ni < 4; ++ni) {
                int n = wc + ni * 16 + n4;
                f32x4 v = acc[mi][ni];
                ushort4 o;
                o.x = f2h(v[0]); o.y = f2h(v[1]); o.z = f2h(v[2]); o.w = f2h(v[3]);
                *(ushort4*)((char*)smC + (m * 256 + ((n * 2) ^ ((m & 7) << 4)))) = o;
            }
        }
    }
    __syncthreads();

    const int lr16 = l & 15;
    const int rg   = l >> 4;
    const int head = (bn < 512) ? (bn >> 7) : ((bn >> 7) - 4);
    const float* ap = att + head * 128 + lr16 * 8;
    float4 aa0 = *(const float4*)(ap);
    float4 aa1 = *(const float4*)(ap + 4);
    const float av[8] = {aa0.x, aa0.y, aa0.z, aa0.w, aa1.x, aa1.y, aa1.z, aa1.w};

    if (bn < 512) {
#pragma unroll
        for (int p = 0; p < 8; ++p) {
            int r = w * 32 + p * 4 + rg;
            uint4 vv = *(const uint4*)((const char*)smC +
                        (r * 256 + ((lr16 * 16) ^ ((r & 7) << 4))));
            f32x2 c0 = __builtin_convertvector(u2h2(vv.x), f32x2);
            f32x2 c1 = __builtin_convertvector(u2h2(vv.y), f32x2);
            f32x2 c2 = __builtin_convertvector(u2h2(vv.z), f32x2);
            f32x2 c3 = __builtin_convertvector(u2h2(vv.w), f32x2);
            float f[8] = {c0[0],c0[1],c1[0],c1[1],c2[0],c2[1],c3[0],c3[1]};
            float m = 0.f, d = 0.f;
#pragma unroll
            for (int k = 0; k < 8; ++k) { m = fmaxf(m, fabsf(f[k])); d += f[k] * av[k]; }
            m = rowmax16(m);
            d = rowsum16(d);
            float inv = (m > 0.f) ? (127.f / m) : 0.f;
            int q[8];
#pragma unroll
            for (int k = 0; k < 8; ++k) {
                int qi = (int)__builtin_rintf(f[k] * inv);
                q[k] = qi > 127 ? 127 : (qi < -127 ? -127 : qi);
            }
            u32 lo = (q[0]&255) | ((q[1]&255)<<8) | ((q[2]&255)<<16) | ((q[3]&255)<<24);
            u32 hi = (q[4]&255) | ((q[5]&255)<<8) | ((q[6]&255)<<16) | ((q[7]&255)<<24);
            uint2 pk; pk.x = lo; pk.y = hi;
            *(uint2*)(XLq + (size_t)(bm + r) * 512 + head * 128 + lr16 * 8) = pk;
            if (lr16 == 0)
                sclD[(bm + r) * 4 + head] =
                    (u32)f2h(m * (1.f / 127.f)) | ((u32)f2h(0.6f * LOG2E * d) << 16);
        }
    } else {
#pragma unroll
        for (int p = 0; p < 8; ++p) {
            int r = w * 32 + p * 4 + rg;
            uint4 vv = *(const uint4*)((const char*)smC +
                        (r * 256 + ((lr16 * 16) ^ ((r & 7) << 4))));
            f32x2 c0 = __builtin_convertvector(u2h2(vv.x), f32x2);
            f32x2 c1 = __builtin_convertvector(u2h2(vv.y), f32x2);
            f32x2 c2 = __builtin_convertvector(u2h2(vv.z), f32x2);
            f32x2 c3 = __builtin_convertvector(u2h2(vv.w), f32x2);
            float f[8] = {c0[0],c0[1],c1[0],c1[1],c2[0],c2[1],c3[0],c3[1]};
            float d = 0.f;
#pragma unroll
            for (int k = 0; k < 8; ++k) d += f[k] * av[k];
            d = rowsum16(d);
            if (lr16 == 0) Dr6[(bm + r) * 4 + head] = f2h(0.6f * LOG2E * d);
        }
        int r  = t >> 4;
        int cb = (t & 15) * 16;
        u16* base = XR + (bn - 512);
#pragma unroll
        for (int p = 0; p < 8; ++p) {
            int row = p * 16 + r;
            uint4 v = *(const uint4*)((const char*)smC +
                        (row * 256 + (cb ^ ((row & 7) << 4))));
            *(uint4*)(base + (size_t)(bm + row) * 512 + (cb >> 1)) = v;
        }
    }
}

// ------------- fused GATv2 attention + head-mean + bias + LN + residual -------------
// R15 2-edge structure + exp2. Residual from f32 (resf) or f16 (resh), whichever non-null.
// f32 out optional (layer-1 skips it; layer-2 reads residual from f16 xb).

__global__ __launch_bounds__(256) void k_attn(const u8*  __restrict__ XLq,
                                              const u32* __restrict__ sclD,
                                              const u16* __restrict__ Dr6,
                                              const u16* __restrict__ XR,
                                              const float* __restrict__ att,
                                              const float* __restrict__ bias,
                                              const float* __restrict__ gamma,
                                              const float* __restrict__ beta,
                                              const int* __restrict__ row,
                                              const int* __restrict__ col,
                                              const float* __restrict__ resf,
                                              const u16* __restrict__ resh,
                                              float* __restrict__ out,
                                              u16* __restrict__ out_h,
                                              int relu_flag) {
    const int wid = __builtin_amdgcn_readfirstlane(threadIdx.x >> 6);
    const int n   = blockIdx.x * 4 + wid;          // grid = NNODES/4 exactly
    const int l   = threadIdx.x & 63;
    const int h   = l >> 4;
    const int e   = l & 15;

    const f16x2 M1152 = {(_Float16)(-1152.f), (_Float16)(-1152.f)};
    const u32 K64 = 0x64646464u;

    const int lane_off = h * 128 + e * 8;

    uint4 xru = *(const uint4*)(XR + (size_t)n * 512 + lane_off);
    f16x2 xr0 = u2h2(xru.x), xr1 = u2h2(xru.y), xr2 = u2h2(xru.z), xr3 = u2h2(xru.w);

    // 0.4*log2e*att in f16 pairs
    const float* ap = att + lane_off;
    float4 af0 = *(const float4*)(ap);
    float4 af1 = *(const float4*)(ap + 4);
    const float AS = 0.4f * LOG2E;
    f16x2 at0 = {(_Float16)(AS*af0.x), (_Float16)(AS*af0.y)};
    f16x2 at1 = {(_Float16)(AS*af0.z), (_Float16)(AS*af0.w)};
    f16x2 at2 = {(_Float16)(AS*af1.x), (_Float16)(AS*af1.y)};
    f16x2 at3 = {(_Float16)(AS*af1.z), (_Float16)(AS*af1.w)};

    const float dr6n = (float)bits2h(Dr6[n * 4 + h]);

    f16x2 acch[4] = {};
    float ssum = 0.f;

    const int beg = row[n], end = row[n + 1];

    for (int i = beg; i < end; i += 2) {
        int s0 = col[i];
        bool has2 = (i + 1 < end);
        int s1 = has2 ? col[i + 1] : s0;

        uint2 a0 = *(const uint2*)(XLq + (size_t)s0 * 512 + lane_off);
        uint2 a1 = *(const uint2*)(XLq + (size_t)s1 * 512 + lane_off);
        u32 sd0 = sclD[s0 * 4 + h];
        u32 sd1 = sclD[s1 * 4 + h];
        _Float16 sh0 = bits2h((u16)sd0);
        _Float16 sh1 = bits2h((u16)sd1);
        float d60 = dr6n + (float)bits2h((u16)(sd0 >> 16));
        float d61 = dr6n + (float)bits2h((u16)(sd1 >> 16));
        f16x2 s0h2 = {sh0, sh0};
        f16x2 s1h2 = {sh1, sh1};

        // magic decode int8 -> f16 (exact)
        u32 w00 = a0.x ^ 0x80808080u, w01 = a0.y ^ 0x80808080u;
        u32 w10 = a1.x ^ 0x80808080u, w11 = a1.y ^ 0x80808080u;
        f16x2 q00 = u2h2(__builtin_amdgcn_perm(K64, w00, 0x04010400u)) + M1152;
        f16x2 q01 = u2h2(__builtin_amdgcn_perm(K64, w00, 0x04030402u)) + M1152;
        f16x2 q02 = u2h2(__builtin_amdgcn_perm(K64, w01, 0x04010400u)) + M1152;
        f16x2 q03 = u2h2(__builtin_amdgcn_perm(K64, w01, 0x04030402u)) + M1152;
        f16x2 q10 = u2h2(__builtin_amdgcn_perm(K64, w10, 0x04010400u)) + M1152;
        f16x2 q11 = u2h2(__builtin_amdgcn_perm(K64, w10, 0x04030402u)) + M1152;
        f16x2 q12 = u2h2(__builtin_amdgcn_perm(K64, w11, 0x04010400u)) + M1152;
        f16x2 q13 = u2h2(__builtin_amdgcn_perm(K64, w11, 0x04030402u)) + M1152;

        float e0, e1;
        {
            f16x2 v0 = q00 * s0h2 + xr0, v1 = q01 * s0h2 + xr1;
            f16x2 v2 = q02 * s0h2 + xr2, v3 = q03 * s0h2 + xr3;
            e0 = __builtin_amdgcn_fdot2(habs2(v0), at0, 0.f, false);
            e0 = __builtin_amdgcn_fdot2(habs2(v1), at1, e0, false);
            e0 = __builtin_amdgcn_fdot2(habs2(v2), at2, e0, false);
            e0 = __builtin_amdgcn_fdot2(habs2(v3), at3, e0, false);
        }
        {
            f16x2 v0 = q10 * s1h2 + xr0, v1 = q11 * s1h2 + xr1;
            f16x2 v2 = q12 * s1h2 + xr2, v3 = q13 * s1h2 + xr3;
            e1 = __builtin_amdgcn_fdot2(habs2(v0), at0, 0.f, false);
            e1 = __builtin_amdgcn_fdot2(habs2(v1), at1, e1, false);
            e1 = __builtin_amdgcn_fdot2(habs2(v2), at2, e1, false);
            e1 = __builtin_amdgcn_fdot2(habs2(v3), at3, e1, false);
        }

        // 16-lane row reduce via DPP (pure VALU), 2 chains interleaved
        e0 += DPP_ROR(e0, 0x121); e1 += DPP_ROR(e1, 0x121);
        e0 += DPP_ROR(e0, 0x122); e1 += DPP_ROR(e1, 0x122);
        e0 += DPP_ROR(e0, 0x124); e1 += DPP_ROR(e1, 0x124);
        e0 += DPP_ROR(e0, 0x128); e1 += DPP_ROR(e1, 0x128);

        float p0 = exp2f(e0 + d60);
        float p1 = has2 ? exp2f(e1 + d61) : 0.f;
        ssum += p0 + p1;

        _Float16 ph0s = (_Float16)(p0 * (float)sh0);
        _Float16 ph1s = (_Float16)(p1 * (float)sh1);
        f16x2 ph0 = {ph0s, ph0s};
        f16x2 ph1 = {ph1s, ph1s};
        acch[0] = acch[0] + ph0 * q00 + ph1 * q10;
        acch[1] = acch[1] + ph0 * q01 + ph1 * q11;
        acch[2] = acch[2] + ph0 * q02 + ph1 * q12;
        acch[3] = acch[3] + ph0 * q03 + ph1 * q13;
    }

    float acc[8];
    {
        f32x2 c;
        c = __builtin_convertvector(acch[0], f32x2); acc[0] = c[0]; acc[1] = c[1];
        c = __builtin_convertvector(acch[1], f32x2); acc[2] = c[0]; acc[3] = c[1];
        c = __builtin_convertvector(acch[2], f32x2); acc[4] = c[0]; acc[5] = c[1];
        c = __builtin_convertvector(acch[3], f32x2); acc[6] = c[0]; acc[7] = c[1];
    }
    float inv = 1.f / (ssum + 1e-16f);
#pragma unroll
    for (int jj = 0; jj < 8; ++jj) acc[jj] *= inv;
#pragma unroll
    for (int jj = 0; jj < 8; ++jj) acc[jj] += __shfl_xor(acc[jj], 16, 64);
#pragma unroll
    for (int jj = 0; jj < 8; ++jj) acc[jj] += __shfl_xor(acc[jj], 32, 64);

    if (h == 0) {
        const int dd = e * 8;
        float4 b40 = *(const float4*)(bias + dd);
        float4 b41 = *(const float4*)(bias + dd + 4);
        float y[8];
        y[0] = acc[0]*0.25f + b40.x; y[1] = acc[1]*0.25f + b40.y;
        y[2] = acc[2]*0.25f + b40.z; y[3] = acc[3]*0.25f + b40.w;
        y[4] = acc[4]*0.25f + b41.x; y[5] = acc[5]*0.25f + b41.y;
        y[6] = acc[6]*0.25f + b41.z; y[7] = acc[7]*0.25f + b41.w;

        float s1 = 0.f, s2 = 0.f;
#pragma unroll
        for (int jj = 0; jj < 8; ++jj) { s1 += y[jj]; s2 += y[jj]*y[jj]; }
#pragma unroll
        for (int m = 1; m < 16; m <<= 1) {
            s1 += __shfl_xor(s1, m, 64);
            s2 += __shfl_xor(s2, m, 64);
        }
        float mu = s1 * (1.f / 128.f);
        float var = s2 * (1.f / 128.f) - mu * mu;
        float rstd = rsqrtf(var + LN_EPS);

        float4 g40 = *(const float4*)(gamma + dd);
        float4 g41 = *(const float4*)(gamma + dd + 4);
        float4 e40 = *(const float4*)(beta + dd);
        float4 e41 = *(const float4*)(beta + dd + 4);
        float g[8] = {g40.x,g40.y,g40.z,g40.w,g41.x,g41.y,g41.z,g41.w};
        float be[8] = {e40.x,e40.y,e40.z,e40.w,e41.x,e41.y,e41.z,e41.w};
        float r[8];
        if (resf) {
            float4 r40 = *(const float4*)(resf + (size_t)n * 128 + dd);
            float4 r41 = *(const float4*)(resf + (size_t)n * 128 + dd + 4);
            r[0]=r40.x; r[1]=r40.y; r[2]=r40.z; r[3]=r40.w;
            r[4]=r41.x; r[5]=r41.y; r[6]=r41.z; r[7]=r41.w;
        } else {
            uint4 rh = *(const uint4*)(resh + (size_t)n * 128 + dd);
            f32x2 c;
            c = __builtin_convertvector(u2h2(rh.x), f32x2); r[0]=c[0]; r[1]=c[1];
            c = __builtin_convertvector(u2h2(rh.y), f32x2); r[2]=c[0]; r[3]=c[1];
            c = __builtin_convertvector(u2h2(rh.z), f32x2); r[4]=c[0]; r[5]=c[1];
            c = __builtin_convertvector(u2h2(rh.w), f32x2); r[6]=c[0]; r[7]=c[1];
        }
#pragma unroll
        for (int jj = 0; jj < 8; ++jj) {
            y[jj] = (y[jj] - mu) * rstd * g[jj] + be[jj] + r[jj];
            if (relu_flag) y[jj] = fmaxf(y[jj], 0.f);
        }
        if (out) {
            float4 o0 = {y[0],y[1],y[2],y[3]};
            float4 o1 = {y[4],y[5],y[6],y[7]};
            *(float4*)(out + (size_t)n * 128 + dd)     = o0;
            *(float4*)(out + (size_t)n * 128 + dd + 4) = o1;
        }
        if (out_h) {
            ushort4 oh0, oh1;
            oh0.x = f2h(y[0]); oh0.y = f2h(y[1]); oh0.z = f2h(y[2]); oh0.w = f2h(y[3]);
            oh1.x = f2h(y[4]); oh1.y = f2h(y[5]); oh1.z = f2h(y[6]); oh1.w = f2h(y[7]);
            *(ushort4*)(out_h + (size_t)n * 128 + dd)     = oh0;
            *(ushort4*)(out_h + (size_t)n * 128 + dd + 4) = oh1;
        }
    }
}

// ---------------- launch ----------------

extern "C" void kernel_launch(void* const* d_in, const int* in_sizes, int n_in,
                              void* d_out, int out_size, void* d_ws, size_t ws_size,
                              hipStream_t stream) {
    const float* x    = (const float*)d_in[0];
    const int*   src  = (const int*)d_in[1];
    const int*   dst  = (const int*)d_in[2];
    const float* Wl1  = (const float*)d_in[3];
    const float* Wr1  = (const float*)d_in[4];
    const float* att1 = (const float*)d_in[5];
    const float* b1   = (const float*)d_in[6];
    const float* g1   = (const float*)d_in[7];
    const float* be1  = (const float*)d_in[8];
    const float* Wl2  = (const float*)d_in[9];
    const float* Wr2  = (const float*)d_in[10];
    const float* att2 = (const float*)d_in[11];
    const float* b2   = (const float*)d_in[12];
    const float* g2   = (const float*)d_in[13];
    const float* be2  = (const float*)d_in[14];
    float* out = (float*)d_out;

    char* ws = (char*)d_ws;
    size_t off = 0;
    u8*    xlq  = (u8*)(ws + off);    off += (size_t)MPAD * 512;          // int8 XL
    u32*   scld = (u32*)(ws + off);   off += (size_t)MPAD * 4 * 4;        // packed scale+Dl6
    u16*   dr6  = (u16*)(ws + off);   off += (size_t)MPAD * 4 * 2;        // Dr6 f16
    u16*   xrb  = (u16*)(ws + off);   off += (size_t)MPAD * 512 * 2;      // f16 XR
    u16*   xb   = (u16*)(ws + off);   off += (size_t)MPAD * 128 * 2;      // f16 A / residual
    u16*   Bt1  = (u16*)(ws + off);   off += (size_t)1024 * 128 * 2;
    u16*   Bt2  = (u16*)(ws + off);   off += (size_t)1024 * 128 * 2;
    int*   deg  = (int*)(ws + off);   off += (size_t)NNODES * 4;
    int*   rowp = (int*)(ws + off);   off += (size_t)(NNODES + 1) * 4;
    int*   cur  = (int*)(ws + off);   off += (size_t)NNODES * 4;
    int*   col  = (int*)(ws + off);   off += (size_t)ETOT * 4;

    k_prep<<<256, 256, 0, stream>>>(x, xb, Wl1, Wr1, Bt1, Wl2, Wr2, Bt2, deg);
    k_hist<<<(NEDGES + 255) / 256, 256, 0, stream>>>(dst, deg);
    k_scan<<<1, 1024, 0, stream>>>(deg, rowp, cur);
    k_scatter<<<(ETOT + 255) / 256, 256, 0, stream>>>(src, dst, col, cur);

    // layer 1: residual = x (f32); output only f16 into xb (becomes layer-2 input+residual)
    k_gemm_f16<<<MPAD / 128 * 8, 256, 0, stream>>>(xb, Bt1, att1, xlq, scld, dr6, xrb);
    k_attn<<<NNODES / 4, 256, 0, stream>>>(xlq, scld, dr6, xrb, att1, b1, g1, be1,
                                           rowp, col, x, (const u16*)nullptr,
                                           (float*)nullptr, xb, 1);
    // layer 2: residual = xb (f16); output f32 to d_out
    k_gemm_f16<<<MPAD / 128 * 8, 256, 0, stream>>>(xb, Bt2, att2, xlq, scld, dr6, xrb);
    k_attn<<<NNODES / 4, 256, 0, stream>>>(xlq, scld, dr6, xrb, att2, b2, g2, be2,
                                           rowp, col, (const float*)nullptr, xb,
                                           out, (u16*)nullptr, 0);
}

// Round 18
// 174.332 us; speedup vs baseline: 1.0555x; 1.0291x over previous
//
#include <hip/hip_runtime.h>
#include <hip/hip_bf16.h>
#include <hip/hip_fp16.h>

#define NNODES 20000
#define MPAD   20480              // 160 * 128 row-tiles, no M-guards anywhere
#define NEDGES 320000
#define DIM    128
#define NH     4
#define ETOT   (NEDGES + NNODES)
#define LN_EPS 1e-5f

typedef unsigned char  u8;
typedef unsigned short u16;
typedef unsigned int   u32;

typedef _Float16    f16x2 __attribute__((ext_vector_type(2)));
typedef _Float16    f16x8 __attribute__((ext_vector_type(8)));
typedef float       f32x2 __attribute__((ext_vector_type(2)));
typedef float       f32x4 __attribute__((ext_vector_type(4)));

__device__ inline u16 f2h(float f) {
    _Float16 h = (_Float16)f;
    union { _Float16 h; u16 u; } v; v.h = h; return v.u;
}
__device__ inline _Float16 bits2h(u16 b) {
    union { u16 u; _Float16 h; } v; v.u = b; return v.h;
}
__device__ inline f16x2 u2h2(u32 u) { union { u32 u; f16x2 h; } v; v.u = u; return v.h; }
__device__ inline u32 h22u(f16x2 h) { union { f16x2 h; u32 u; } v; v.h = h; return v.u; }
__device__ inline f16x2 habs2(f16x2 h) { return u2h2(h22u(h) & 0x7FFF7FFFu); }

// DPP row_ror rotate (16-lane row), pure-VALU cross-lane
#define DPP_ROR(x, ctrl) ({ union {float f; int i;} _a, _b; _a.f=(x); \
    _b.i = __builtin_amdgcn_update_dpp(0, _a.i, (ctrl), 0xF, 0xF, true); _b.f; })
__device__ inline float rowsum16(float x) {
    x += DPP_ROR(x, 0x121); x += DPP_ROR(x, 0x122);
    x += DPP_ROR(x, 0x124); x += DPP_ROR(x, 0x128);
    return x;
}
__device__ inline float rowmax16(float x) {
    x = fmaxf(x, DPP_ROR(x, 0x121)); x = fmaxf(x, DPP_ROR(x, 0x122));
    x = fmaxf(x, DPP_ROR(x, 0x124)); x = fmaxf(x, DPP_ROR(x, 0x128));
    return x;
}

// async global->LDS, 16B per lane, linear LDS dest
#define GLDS16(g, l) __builtin_amdgcn_global_load_lds(                         \
    (const __attribute__((address_space(1))) void*)(g),                        \
    (__attribute__((address_space(3))) void*)(l), 16, 0, 0)

// ---- fused prep: deg init + x->f16 + W->Bt via LDS transpose ----

__global__ __launch_bounds__(256) void k_prep(const float* __restrict__ x, u16* __restrict__ xb,
                       const float* __restrict__ Wl1, const float* __restrict__ Wr1,
                       u16* __restrict__ Bt1,
                       const float* __restrict__ Wl2, const float* __restrict__ Wr2,
                       u16* __restrict__ Bt2,
                       int* __restrict__ deg) {
    const int b = blockIdx.x, t = threadIdx.x;
    const int gid = b * 256 + t;
    if (gid < NNODES) deg[gid] = 1;   // self-loop

    for (int j = gid; j < NNODES * 32; j += 256 * 256) {
        float4 v = ((const float4*)x)[j];
        ushort4 o;
        o.x = f2h(v.x); o.y = f2h(v.y); o.z = f2h(v.z); o.w = f2h(v.w);
        ((ushort4*)xb)[j] = o;
    }

    {
        const int m    = b >> 6;
        const int tile = b & 63;
        const int kt   = tile >> 4;
        const int nt   = tile & 15;
        const float* W = (m == 0) ? Wl1 : (m == 1) ? Wr1 : (m == 2) ? Wl2 : Wr2;
        u16* Bt        = (m < 2) ? Bt1 : Bt2;
        const int nbase = (m & 1) * 512 + nt * 32;

        __shared__ float lds[32][33];
        const int tx = t & 31, ty = t >> 5;
#pragma unroll
        for (int i = 0; i < 4; ++i) {
            int k = kt * 32 + ty + i * 8;
            lds[ty + i * 8][tx] = W[k * 512 + nt * 32 + tx];
        }
        __syncthreads();
#pragma unroll
        for (int i = 0; i < 4; ++i) {
            int nrow = nbase + ty + i * 8;
            Bt[nrow * 128 + kt * 32 + tx] = f2h(lds[tx][ty + i * 8]);
        }
    }
}

// ---------------- CSR build ----------------

__global__ void k_hist(const int* __restrict__ dst, int* __restrict__ deg) {
    int i = blockIdx.x * blockDim.x + threadIdx.x;
    if (i < NEDGES) atomicAdd(&deg[dst[i]], 1);
}

__global__ __launch_bounds__(1024) void k_scan(const int* __restrict__ deg,
                                               int* __restrict__ row,
                                               int* __restrict__ cur) {
    __shared__ int part[1024];
    const int CH = 20;
    int t = threadIdx.x;
    int base = t * CH;
    int s = 0;
    int d[20];
    if (base < NNODES) {
#pragma unroll
        for (int q = 0; q < 5; ++q) {
            int4 v = ((const int4*)(deg + base))[q];
            d[q*4+0] = v.x; d[q*4+1] = v.y; d[q*4+2] = v.z; d[q*4+3] = v.w;
            s += v.x + v.y + v.z + v.w;
        }
    }
    part[t] = s;
    __syncthreads();
    for (int off = 1; off < 1024; off <<= 1) {
        int v = (t >= off) ? part[t - off] : 0;
        __syncthreads();
        part[t] += v;
        __syncthreads();
    }
    if (base < NNODES) {
        int run = (t == 0) ? 0 : part[t - 1];
#pragma unroll
        for (int i = 0; i < CH; i++) {
            row[base + i] = run; cur[base + i] = run; run += d[i];
        }
    }
    if (t == 1023) row[NNODES] = part[1023];
}

__global__ void k_scatter(const int* __restrict__ src, const int* __restrict__ dst,
                          int* __restrict__ col, int* __restrict__ cur) {
    int i = blockIdx.x * blockDim.x + threadIdx.x;
    if (i < NEDGES) {
        int d = dst[i];
        int pos = atomicAdd(&cur[d], 1);
        col[pos] = src[i];
    } else if (i < ETOT) {
        int n = i - NEDGES;
        int pos = atomicAdd(&cur[n], 1);
        col[pos] = n;
    }
}

// ------------- fp16 MFMA GEMM + fused int8 quant + fused att-dot precompute -------------
// Dl6 = 0.6*dot(xl,att) packed with scale; Dr6 = 0.6*dot(xr,att). (natural-log domain)

__global__ __launch_bounds__(256, 2) void k_gemm_f16(const u16* __restrict__ A,
                                                     const u16* __restrict__ Bt,
                                                     const float* __restrict__ att,
                                                     u8*  __restrict__ XLq,
                                                     u32* __restrict__ sclD,
                                                     u16* __restrict__ Dr6,
                                                     u16* __restrict__ XR) {
    __shared__ u16 smA[128 * 128];
    __shared__ u16 smB[128 * 128];
    const int L   = blockIdx.x;
    const int xcd = L & 7;
    const int w9  = L >> 3;
    const int bm  = (xcd * 20 + (w9 >> 3)) * 128;
    const int bn  = (w9 & 7) * 128;
    const int t  = threadIdx.x;
    const int w  = t >> 6;
    const int l  = t & 63;

    {
        char* smAb = (char*)smA;
        char* smBb = (char*)smB;
#pragma unroll
        for (int p = 0; p < 8; ++p) {
            int rbase = w * 32 + p * 4;
            int row   = rbase + (l >> 4);
            int j     = (l & 15) ^ (row & 7);
            const u16* ga = A  + (size_t)(bm + row) * 128 + j * 8;
            const u16* gb = Bt + (size_t)(bn + row) * 128 + j * 8;
            GLDS16(ga, smAb + rbase * 256);
            GLDS16(gb, smBb + rbase * 256);
        }
    }
    __syncthreads();

    const int wr  = (w >> 1) * 64;
    const int wc  = (w & 1) * 64;
    const int lr  = l & 15;
    const int lkb = (l >> 4) * 16;

    f32x4 acc[4][4] = {};

#pragma unroll
    for (int ks = 0; ks < 4; ++ks) {
        f16x8 af[4], bfr[4];
#pragma unroll
        for (int i = 0; i < 4; ++i) {
            int ra = wr + i * 16 + lr;
            af[i]  = *(const f16x8*)((const char*)smA +
                        ((ra * 256 + ks * 64 + lkb) ^ ((ra & 7) << 4)));
            int rb = wc + i * 16 + lr;
            bfr[i] = *(const f16x8*)((const char*)smB +
                        ((rb * 256 + ks * 64 + lkb) ^ ((rb & 7) << 4)));
        }
#pragma unroll
        for (int mi = 0; mi < 4; ++mi)
#pragma unroll
            for (int ni = 0; ni < 4; ++ni)
                acc[mi][ni] = __builtin_amdgcn_mfma_f32_16x16x32_f16(
                    bfr[ni], af[mi], acc[mi][ni], 0, 0, 0);
    }

    __syncthreads();
    u16* smC = smA;
    {
        const int n4 = (l >> 4) * 4;
#pragma unroll
        for (int mi = 0; mi < 4; ++mi) {
            int m = wr + mi * 16 + lr;
#pragma unroll
            for (int ni = 0; ni < 4; ++ni) {
                int n = wc + ni * 16 + n4;
                f32x4 v = acc[mi][ni];
                ushort4 o;
                o.x = f2h(v[0]); o.y = f2h(v[1]); o.z = f2h(v[2]); o.w = f2h(v[3]);
                *(ushort4*)((char*)smC + (m * 256 + ((n * 2) ^ ((m & 7) << 4)))) = o;
            }
        }
    }
    __syncthreads();

    const int lr16 = l & 15;
    const int rg   = l >> 4;
    const int head = (bn < 512) ? (bn >> 7) : ((bn >> 7) - 4);
    const float* ap = att + head * 128 + lr16 * 8;
    float4 aa0 = *(const float4*)(ap);
    float4 aa1 = *(const float4*)(ap + 4);
    const float av[8] = {aa0.x, aa0.y, aa0.z, aa0.w, aa1.x, aa1.y, aa1.z, aa1.w};

    if (bn < 512) {
#pragma unroll
        for (int p = 0; p < 8; ++p) {
            int r = w * 32 + p * 4 + rg;
            uint4 vv = *(const uint4*)((const char*)smC +
                        (r * 256 + ((lr16 * 16) ^ ((r & 7) << 4))));
            f32x2 c0 = __builtin_convertvector(u2h2(vv.x), f32x2);
            f32x2 c1 = __builtin_convertvector(u2h2(vv.y), f32x2);
            f32x2 c2 = __builtin_convertvector(u2h2(vv.z), f32x2);
            f32x2 c3 = __builtin_convertvector(u2h2(vv.w), f32x2);
            float f[8] = {c0[0],c0[1],c1[0],c1[1],c2[0],c2[1],c3[0],c3[1]};
            float m = 0.f, d = 0.f;
#pragma unroll
            for (int k = 0; k < 8; ++k) { m = fmaxf(m, fabsf(f[k])); d += f[k] * av[k]; }
            m = rowmax16(m);
            d = rowsum16(d);
            float inv = (m > 0.f) ? (127.f / m) : 0.f;
            int q[8];
#pragma unroll
            for (int k = 0; k < 8; ++k) {
                int qi = (int)__builtin_rintf(f[k] * inv);
                q[k] = qi > 127 ? 127 : (qi < -127 ? -127 : qi);
            }
            u32 lo = (q[0]&255) | ((q[1]&255)<<8) | ((q[2]&255)<<16) | ((q[3]&255)<<24);
            u32 hi = (q[4]&255) | ((q[5]&255)<<8) | ((q[6]&255)<<16) | ((q[7]&255)<<24);
            uint2 pk; pk.x = lo; pk.y = hi;
            *(uint2*)(XLq + (size_t)(bm + r) * 512 + head * 128 + lr16 * 8) = pk;
            if (lr16 == 0)
                sclD[(bm + r) * 4 + head] =
                    (u32)f2h(m * (1.f / 127.f)) | ((u32)f2h(0.6f * d) << 16);
        }
    } else {
#pragma unroll
        for (int p = 0; p < 8; ++p) {
            int r = w * 32 + p * 4 + rg;
            uint4 vv = *(const uint4*)((const char*)smC +
                        (r * 256 + ((lr16 * 16) ^ ((r & 7) << 4))));
            f32x2 c0 = __builtin_convertvector(u2h2(vv.x), f32x2);
            f32x2 c1 = __builtin_convertvector(u2h2(vv.y), f32x2);
            f32x2 c2 = __builtin_convertvector(u2h2(vv.z), f32x2);
            f32x2 c3 = __builtin_convertvector(u2h2(vv.w), f32x2);
            float f[8] = {c0[0],c0[1],c1[0],c1[1],c2[0],c2[1],c3[0],c3[1]};
            float d = 0.f;
#pragma unroll
            for (int k = 0; k < 8; ++k) d += f[k] * av[k];
            d = rowsum16(d);
            if (lr16 == 0) Dr6[(bm + r) * 4 + head] = f2h(0.6f * d);
        }
        int r  = t >> 4;
        int cb = (t & 15) * 16;
        u16* base = XR + (bn - 512);
#pragma unroll
        for (int p = 0; p < 8; ++p) {
            int row = p * 16 + r;
            uint4 v = *(const uint4*)((const char*)smC +
                        (row * 256 + (cb ^ ((row & 7) << 4))));
            *(uint4*)(base + (size_t)(bm + row) * 512 + (cb >> 1)) = v;
        }
    }
}

// ------------- fused GATv2 attention + head-mean + bias + LN + residual -------------
// EXACT R15-bench inner loop (proven 48.7us): __expf, 0.6/0.4 natural-log split,
// 2-edge pairs, DPP reduce. Epilogue: dual residual (f32 or f16), optional outputs.

__global__ __launch_bounds__(256) void k_attn(const u8*  __restrict__ XLq,
                                              const u32* __restrict__ sclD,
                                              const u16* __restrict__ Dr6,
                                              const u16* __restrict__ XR,
                                              const float* __restrict__ att,
                                              const float* __restrict__ bias,
                                              const float* __restrict__ gamma,
                                              const float* __restrict__ beta,
                                              const int* __restrict__ row,
                                              const int* __restrict__ col,
                                              const float* __restrict__ resf,
                                              const u16* __restrict__ resh,
                                              float* __restrict__ out,
                                              u16* __restrict__ out_h,
                                              int relu_flag) {
    const int wid = __builtin_amdgcn_readfirstlane(threadIdx.x >> 6);
    const int n   = blockIdx.x * 4 + wid;          // grid = NNODES/4 exactly
    const int l   = threadIdx.x & 63;
    const int h   = l >> 4;
    const int e   = l & 15;

    const f16x2 M1152 = {(_Float16)(-1152.f), (_Float16)(-1152.f)};
    const u32 K64 = 0x64646464u;

    const int lane_off = h * 128 + e * 8;

    uint4 xru = *(const uint4*)(XR + (size_t)n * 512 + lane_off);
    f16x2 xr0 = u2h2(xru.x), xr1 = u2h2(xru.y), xr2 = u2h2(xru.z), xr3 = u2h2(xru.w);

    // 0.4*att in f16 pairs
    const float* ap = att + lane_off;
    float4 af0 = *(const float4*)(ap);
    float4 af1 = *(const float4*)(ap + 4);
    f16x2 at0 = {(_Float16)(0.4f*af0.x), (_Float16)(0.4f*af0.y)};
    f16x2 at1 = {(_Float16)(0.4f*af0.z), (_Float16)(0.4f*af0.w)};
    f16x2 at2 = {(_Float16)(0.4f*af1.x), (_Float16)(0.4f*af1.y)};
    f16x2 at3 = {(_Float16)(0.4f*af1.z), (_Float16)(0.4f*af1.w)};

    const float dr6n = (float)bits2h(Dr6[n * 4 + h]);   // 0.6*dot(xr_n, att_h)

    f16x2 acch[4] = {};
    float ssum = 0.f;

    const int beg = row[n], end = row[n + 1];

    for (int i = beg; i < end; i += 2) {
        int s0 = col[i];
        bool has2 = (i + 1 < end);
        int s1 = has2 ? col[i + 1] : s0;

        uint2 a0 = *(const uint2*)(XLq + (size_t)s0 * 512 + lane_off);
        uint2 a1 = *(const uint2*)(XLq + (size_t)s1 * 512 + lane_off);
        u32 sd0 = sclD[s0 * 4 + h];
        u32 sd1 = sclD[s1 * 4 + h];
        _Float16 sh0 = bits2h((u16)sd0);
        _Float16 sh1 = bits2h((u16)sd1);
        float d60 = dr6n + (float)bits2h((u16)(sd0 >> 16));
        float d61 = dr6n + (float)bits2h((u16)(sd1 >> 16));
        f16x2 s0h2 = {sh0, sh0};
        f16x2 s1h2 = {sh1, sh1};

        // magic decode int8 -> f16 (exact)
        u32 w00 = a0.x ^ 0x80808080u, w01 = a0.y ^ 0x80808080u;
        u32 w10 = a1.x ^ 0x80808080u, w11 = a1.y ^ 0x80808080u;
        f16x2 q00 = u2h2(__builtin_amdgcn_perm(K64, w00, 0x04010400u)) + M1152;
        f16x2 q01 = u2h2(__builtin_amdgcn_perm(K64, w00, 0x04030402u)) + M1152;
        f16x2 q02 = u2h2(__builtin_amdgcn_perm(K64, w01, 0x04010400u)) + M1152;
        f16x2 q03 = u2h2(__builtin_amdgcn_perm(K64, w01, 0x04030402u)) + M1152;
        f16x2 q10 = u2h2(__builtin_amdgcn_perm(K64, w10, 0x04010400u)) + M1152;
        f16x2 q11 = u2h2(__builtin_amdgcn_perm(K64, w10, 0x04030402u)) + M1152;
        f16x2 q12 = u2h2(__builtin_amdgcn_perm(K64, w11, 0x04010400u)) + M1152;
        f16x2 q13 = u2h2(__builtin_amdgcn_perm(K64, w11, 0x04030402u)) + M1152;

        float e0, e1;
        {
            f16x2 v0 = q00 * s0h2 + xr0, v1 = q01 * s0h2 + xr1;
            f16x2 v2 = q02 * s0h2 + xr2, v3 = q03 * s0h2 + xr3;
            e0 = __builtin_amdgcn_fdot2(habs2(v0), at0, 0.f, false);
            e0 = __builtin_amdgcn_fdot2(habs2(v1), at1, e0, false);
            e0 = __builtin_amdgcn_fdot2(habs2(v2), at2, e0, false);
            e0 = __builtin_amdgcn_fdot2(habs2(v3), at3, e0, false);
        }
        {
            f16x2 v0 = q10 * s1h2 + xr0, v1 = q11 * s1h2 + xr1;
            f16x2 v2 = q12 * s1h2 + xr2, v3 = q13 * s1h2 + xr3;
            e1 = __builtin_amdgcn_fdot2(habs2(v0), at0, 0.f, false);
            e1 = __builtin_amdgcn_fdot2(habs2(v1), at1, e1, false);
            e1 = __builtin_amdgcn_fdot2(habs2(v2), at2, e1, false);
            e1 = __builtin_amdgcn_fdot2(habs2(v3), at3, e1, false);
        }

        // 16-lane row reduce via DPP (pure VALU), interleaved for ILP
        e0 += DPP_ROR(e0, 0x121); e1 += DPP_ROR(e1, 0x121);
        e0 += DPP_ROR(e0, 0x122); e1 += DPP_ROR(e1, 0x122);
        e0 += DPP_ROR(e0, 0x124); e1 += DPP_ROR(e1, 0x124);
        e0 += DPP_ROR(e0, 0x128); e1 += DPP_ROR(e1, 0x128);

        float p0 = __expf(e0 + d60);
        float p1 = has2 ? __expf(e1 + d61) : 0.f;
        ssum += p0 + p1;

        _Float16 ph0s = (_Float16)(p0 * (float)sh0);
        _Float16 ph1s = (_Float16)(p1 * (float)sh1);
        f16x2 ph0 = {ph0s, ph0s};
        f16x2 ph1 = {ph1s, ph1s};
        acch[0] = acch[0] + ph0 * q00 + ph1 * q10;
        acch[1] = acch[1] + ph0 * q01 + ph1 * q11;
        acch[2] = acch[2] + ph0 * q02 + ph1 * q12;
        acch[3] = acch[3] + ph0 * q03 + ph1 * q13;
    }

    float acc[8];
    {
        f32x2 c;
        c = __builtin_convertvector(acch[0], f32x2); acc[0] = c[0]; acc[1] = c[1];
        c = __builtin_convertvector(acch[1], f32x2); acc[2] = c[0]; acc[3] = c[1];
        c = __builtin_convertvector(acch[2], f32x2); acc[4] = c[0]; acc[5] = c[1];
        c = __builtin_convertvector(acch[3], f32x2); acc[6] = c[0]; acc[7] = c[1];
    }
    float inv = 1.f / (ssum + 1e-16f);
#pragma unroll
    for (int jj = 0; jj < 8; ++jj) acc[jj] *= inv;
#pragma unroll
    for (int jj = 0; jj < 8; ++jj) acc[jj] += __shfl_xor(acc[jj], 16, 64);
#pragma unroll
    for (int jj = 0; jj < 8; ++jj) acc[jj] += __shfl_xor(acc[jj], 32, 64);

    if (h == 0) {
        const int dd = e * 8;
        float4 b40 = *(const float4*)(bias + dd);
        float4 b41 = *(const float4*)(bias + dd + 4);
        float y[8];
        y[0] = acc[0]*0.25f + b40.x; y[1] = acc[1]*0.25f + b40.y;
        y[2] = acc[2]*0.25f + b40.z; y[3] = acc[3]*0.25f + b40.w;
        y[4] = acc[4]*0.25f + b41.x; y[5] = acc[5]*0.25f + b41.y;
        y[6] = acc[6]*0.25f + b41.z; y[7] = acc[7]*0.25f + b41.w;

        float s1 = 0.f, s2 = 0.f;
#pragma unroll
        for (int jj = 0; jj < 8; ++jj) { s1 += y[jj]; s2 += y[jj]*y[jj]; }
#pragma unroll
        for (int m = 1; m < 16; m <<= 1) {
            s1 += __shfl_xor(s1, m, 64);
            s2 += __shfl_xor(s2, m, 64);
        }
        float mu = s1 * (1.f / 128.f);
        float var = s2 * (1.f / 128.f) - mu * mu;
        float rstd = rsqrtf(var + LN_EPS);

        float4 g40 = *(const float4*)(gamma + dd);
        float4 g41 = *(const float4*)(gamma + dd + 4);
        float4 e40 = *(const float4*)(beta + dd);
        float4 e41 = *(const float4*)(beta + dd + 4);
        float g[8] = {g40.x,g40.y,g40.z,g40.w,g41.x,g41.y,g41.z,g41.w};
        float be[8] = {e40.x,e40.y,e40.z,e40.w,e41.x,e41.y,e41.z,e41.w};
        float r[8];
        if (resf) {
            float4 r40 = *(const float4*)(resf + (size_t)n * 128 + dd);
            float4 r41 = *(const float4*)(resf + (size_t)n * 128 + dd + 4);
            r[0]=r40.x; r[1]=r40.y; r[2]=r40.z; r[3]=r40.w;
            r[4]=r41.x; r[5]=r41.y; r[6]=r41.z; r[7]=r41.w;
        } else {
            uint4 rh = *(const uint4*)(resh + (size_t)n * 128 + dd);
            f32x2 c;
            c = __builtin_convertvector(u2h2(rh.x), f32x2); r[0]=c[0]; r[1]=c[1];
            c = __builtin_convertvector(u2h2(rh.y), f32x2); r[2]=c[0]; r[3]=c[1];
            c = __builtin_convertvector(u2h2(rh.z), f32x2); r[4]=c[0]; r[5]=c[1];
            c = __builtin_convertvector(u2h2(rh.w), f32x2); r[6]=c[0]; r[7]=c[1];
        }
#pragma unroll
        for (int jj = 0; jj < 8; ++jj) {
            y[jj] = (y[jj] - mu) * rstd * g[jj] + be[jj] + r[jj];
            if (relu_flag) y[jj] = fmaxf(y[jj], 0.f);
        }
        if (out) {
            float4 o0 = {y[0],y[1],y[2],y[3]};
            float4 o1 = {y[4],y[5],y[6],y[7]};
            *(float4*)(out + (size_t)n * 128 + dd)     = o0;
            *(float4*)(out + (size_t)n * 128 + dd + 4) = o1;
        }
        if (out_h) {
            ushort4 oh0, oh1;
            oh0.x = f2h(y[0]); oh0.y = f2h(y[1]); oh0.z = f2h(y[2]); oh0.w = f2h(y[3]);
            oh1.x = f2h(y[4]); oh1.y = f2h(y[5]); oh1.z = f2h(y[6]); oh1.w = f2h(y[7]);
            *(ushort4*)(out_h + (size_t)n * 128 + dd)     = oh0;
            *(ushort4*)(out_h + (size_t)n * 128 + dd + 4) = oh1;
        }
    }
}

// ---------------- launch ----------------

extern "C" void kernel_launch(void* const* d_in, const int* in_sizes, int n_in,
                              void* d_out, int out_size, void* d_ws, size_t ws_size,
                              hipStream_t stream) {
    const float* x    = (const float*)d_in[0];
    const int*   src  = (const int*)d_in[1];
    const int*   dst  = (const int*)d_in[2];
    const float* Wl1  = (const float*)d_in[3];
    const float* Wr1  = (const float*)d_in[4];
    const float* att1 = (const float*)d_in[5];
    const float* b1   = (const float*)d_in[6];
    const float* g1   = (const float*)d_in[7];
    const float* be1  = (const float*)d_in[8];
    const float* Wl2  = (const float*)d_in[9];
    const float* Wr2  = (const float*)d_in[10];
    const float* att2 = (const float*)d_in[11];
    const float* b2   = (const float*)d_in[12];
    const float* g2   = (const float*)d_in[13];
    const float* be2  = (const float*)d_in[14];
    float* out = (float*)d_out;

    char* ws = (char*)d_ws;
    size_t off = 0;
    u8*    xlq  = (u8*)(ws + off);    off += (size_t)MPAD * 512;          // int8 XL
    u32*   scld = (u32*)(ws + off);   off += (size_t)MPAD * 4 * 4;        // packed scale+Dl6
    u16*   dr6  = (u16*)(ws + off);   off += (size_t)MPAD * 4 * 2;        // Dr6 f16
    u16*   xrb  = (u16*)(ws + off);   off += (size_t)MPAD * 512 * 2;      // f16 XR
    u16*   xb   = (u16*)(ws + off);   off += (size_t)MPAD * 128 * 2;      // f16 A / residual
    u16*   Bt1  = (u16*)(ws + off);   off += (size_t)1024 * 128 * 2;
    u16*   Bt2  = (u16*)(ws + off);   off += (size_t)1024 * 128 * 2;
    int*   deg  = (int*)(ws + off);   off += (size_t)NNODES * 4;
    int*   rowp = (int*)(ws + off);   off += (size_t)(NNODES + 1) * 4;
    int*   cur  = (int*)(ws + off);   off += (size_t)NNODES * 4;
    int*   col  = (int*)(ws + off);   off += (size_t)ETOT * 4;

    k_prep<<<256, 256, 0, stream>>>(x, xb, Wl1, Wr1, Bt1, Wl2, Wr2, Bt2, deg);
    k_hist<<<(NEDGES + 255) / 256, 256, 0, stream>>>(dst, deg);
    k_scan<<<1, 1024, 0, stream>>>(deg, rowp, cur);
    k_scatter<<<(ETOT + 255) / 256, 256, 0, stream>>>(src, dst, col, cur);

    // layer 1: residual = x (f32); output only f16 into xb (becomes layer-2 input+residual)
    k_gemm_f16<<<MPAD / 128 * 8, 256, 0, stream>>>(xb, Bt1, att1, xlq, scld, dr6, xrb);
    k_attn<<<NNODES / 4, 256, 0, stream>>>(xlq, scld, dr6, xrb, att1, b1, g1, be1,
                                           rowp, col, x, (const u16*)nullptr,
                                           (float*)nullptr, xb, 1);
    // layer 2: residual = xb (f16); output f32 to d_out
    k_gemm_f16<<<MPAD / 128 * 8, 256, 0, stream>>>(xb, Bt2, att2, xlq, scld, dr6, xrb);
    k_attn<<<NNODES / 4, 256, 0, stream>>>(xlq, scld, dr6, xrb, att2, b2, g2, be2,
                                           rowp, col, (const float*)nullptr, xb,
                                           out, (u16*)nullptr, 0);
}

// Round 19
// 172.543 us; speedup vs baseline: 1.0664x; 1.0104x over previous
//
#include <hip/hip_runtime.h>
#include <hip/hip_bf16.h>
#include <hip/hip_fp16.h>

#define NNODES 20000
#define MPAD   20480              // 160 * 128 row-tiles, no M-guards anywhere
#define NEDGES 320000
#define DIM    128
#define NH     4
#define ETOT   (NEDGES + NNODES)
#define LN_EPS 1e-5f

typedef unsigned char  u8;
typedef unsigned short u16;
typedef unsigned int   u32;

typedef _Float16    f16x2 __attribute__((ext_vector_type(2)));
typedef _Float16    f16x8 __attribute__((ext_vector_type(8)));
typedef float       f32x2 __attribute__((ext_vector_type(2)));
typedef float       f32x4 __attribute__((ext_vector_type(4)));

__device__ inline u16 f2h(float f) {
    _Float16 h = (_Float16)f;
    union { _Float16 h; u16 u; } v; v.h = h; return v.u;
}
__device__ inline _Float16 bits2h(u16 b) {
    union { u16 u; _Float16 h; } v; v.u = b; return v.h;
}
__device__ inline f16x2 u2h2(u32 u) { union { u32 u; f16x2 h; } v; v.u = u; return v.h; }
__device__ inline u32 h22u(f16x2 h) { union { f16x2 h; u32 u; } v; v.h = h; return v.u; }
__device__ inline f16x2 habs2(f16x2 h) { return u2h2(h22u(h) & 0x7FFF7FFFu); }

// DPP row_ror rotate (16-lane row), pure-VALU cross-lane
#define DPP_ROR(x, ctrl) ({ union {float f; int i;} _a, _b; _a.f=(x); \
    _b.i = __builtin_amdgcn_update_dpp(0, _a.i, (ctrl), 0xF, 0xF, true); _b.f; })
__device__ inline float rowsum16(float x) {
    x += DPP_ROR(x, 0x121); x += DPP_ROR(x, 0x122);
    x += DPP_ROR(x, 0x124); x += DPP_ROR(x, 0x128);
    return x;
}
__device__ inline float rowmax16(float x) {
    x = fmaxf(x, DPP_ROR(x, 0x121)); x = fmaxf(x, DPP_ROR(x, 0x122));
    x = fmaxf(x, DPP_ROR(x, 0x124)); x = fmaxf(x, DPP_ROR(x, 0x128));
    return x;
}

// async global->LDS, 16B per lane, linear LDS dest
#define GLDS16(g, l) __builtin_amdgcn_global_load_lds(                         \
    (const __attribute__((address_space(1))) void*)(g),                        \
    (__attribute__((address_space(3))) void*)(l), 16, 0, 0)

// ---- fused prep: deg init + x->f16 + W->Bt via LDS transpose ----

__global__ __launch_bounds__(256) void k_prep(const float* __restrict__ x, u16* __restrict__ xb,
                       const float* __restrict__ Wl1, const float* __restrict__ Wr1,
                       u16* __restrict__ Bt1,
                       const float* __restrict__ Wl2, const float* __restrict__ Wr2,
                       u16* __restrict__ Bt2,
                       int* __restrict__ deg) {
    const int b = blockIdx.x, t = threadIdx.x;
    const int gid = b * 256 + t;
    if (gid < NNODES) deg[gid] = 1;   // self-loop

    for (int j = gid; j < NNODES * 32; j += 256 * 256) {
        float4 v = ((const float4*)x)[j];
        ushort4 o;
        o.x = f2h(v.x); o.y = f2h(v.y); o.z = f2h(v.z); o.w = f2h(v.w);
        ((ushort4*)xb)[j] = o;
    }

    {
        const int m    = b >> 6;
        const int tile = b & 63;
        const int kt   = tile >> 4;
        const int nt   = tile & 15;
        const float* W = (m == 0) ? Wl1 : (m == 1) ? Wr1 : (m == 2) ? Wl2 : Wr2;
        u16* Bt        = (m < 2) ? Bt1 : Bt2;
        const int nbase = (m & 1) * 512 + nt * 32;

        __shared__ float lds[32][33];
        const int tx = t & 31, ty = t >> 5;
#pragma unroll
        for (int i = 0; i < 4; ++i) {
            int k = kt * 32 + ty + i * 8;
            lds[ty + i * 8][tx] = W[k * 512 + nt * 32 + tx];
        }
        __syncthreads();
#pragma unroll
        for (int i = 0; i < 4; ++i) {
            int nrow = nbase + ty + i * 8;
            Bt[nrow * 128 + kt * 32 + tx] = f2h(lds[tx][ty + i * 8]);
        }
    }
}

// ---------------- CSR build ----------------

__global__ void k_hist(const int* __restrict__ dst, int* __restrict__ deg) {
    int i = blockIdx.x * blockDim.x + threadIdx.x;
    if (i < NEDGES) atomicAdd(&deg[dst[i]], 1);
}

__global__ __launch_bounds__(1024) void k_scan(const int* __restrict__ deg,
                                               int* __restrict__ row,
                                               int* __restrict__ cur) {
    __shared__ int part[1024];
    const int CH = 20;
    int t = threadIdx.x;
    int base = t * CH;
    int s = 0;
    int d[20];
    if (base < NNODES) {
#pragma unroll
        for (int q = 0; q < 5; ++q) {
            int4 v = ((const int4*)(deg + base))[q];
            d[q*4+0] = v.x; d[q*4+1] = v.y; d[q*4+2] = v.z; d[q*4+3] = v.w;
            s += v.x + v.y + v.z + v.w;
        }
    }
    part[t] = s;
    __syncthreads();
    for (int off = 1; off < 1024; off <<= 1) {
        int v = (t >= off) ? part[t - off] : 0;
        __syncthreads();
        part[t] += v;
        __syncthreads();
    }
    if (base < NNODES) {
        int run = (t == 0) ? 0 : part[t - 1];
#pragma unroll
        for (int i = 0; i < CH; i++) {
            row[base + i] = run; cur[base + i] = run; run += d[i];
        }
    }
    if (t == 1023) row[NNODES] = part[1023];
}

__global__ void k_scatter(const int* __restrict__ src, const int* __restrict__ dst,
                          int* __restrict__ col, int* __restrict__ cur) {
    int i = blockIdx.x * blockDim.x + threadIdx.x;
    if (i < NEDGES) {
        int d = dst[i];
        int pos = atomicAdd(&cur[d], 1);
        col[pos] = src[i];
    } else if (i < ETOT) {
        int n = i - NEDGES;
        int pos = atomicAdd(&cur[n], 1);
        col[pos] = n;
    }
}

// ------------- fp16 MFMA GEMM + fused int8 quant + fused att-dot precompute -------------
// Dl6 = 0.6*dot(xl,att) packed with scale; Dr6 = 0.6*dot(xr,att). (natural-log domain)

__global__ __launch_bounds__(256, 2) void k_gemm_f16(const u16* __restrict__ A,
                                                     const u16* __restrict__ Bt,
                                                     const float* __restrict__ att,
                                                     u8*  __restrict__ XLq,
                                                     u32* __restrict__ sclD,
                                                     u16* __restrict__ Dr6,
                                                     u16* __restrict__ XR) {
    __shared__ u16 smA[128 * 128];
    __shared__ u16 smB[128 * 128];
    const int L   = blockIdx.x;
    const int xcd = L & 7;
    const int w9  = L >> 3;
    const int bm  = (xcd * 20 + (w9 >> 3)) * 128;
    const int bn  = (w9 & 7) * 128;
    const int t  = threadIdx.x;
    const int w  = t >> 6;
    const int l  = t & 63;

    {
        char* smAb = (char*)smA;
        char* smBb = (char*)smB;
#pragma unroll
        for (int p = 0; p < 8; ++p) {
            int rbase = w * 32 + p * 4;
            int row   = rbase + (l >> 4);
            int j     = (l & 15) ^ (row & 7);
            const u16* ga = A  + (size_t)(bm + row) * 128 + j * 8;
            const u16* gb = Bt + (size_t)(bn + row) * 128 + j * 8;
            GLDS16(ga, smAb + rbase * 256);
            GLDS16(gb, smBb + rbase * 256);
        }
    }
    __syncthreads();

    const int wr  = (w >> 1) * 64;
    const int wc  = (w & 1) * 64;
    const int lr  = l & 15;
    const int lkb = (l >> 4) * 16;

    f32x4 acc[4][4] = {};

#pragma unroll
    for (int ks = 0; ks < 4; ++ks) {
        f16x8 af[4], bfr[4];
#pragma unroll
        for (int i = 0; i < 4; ++i) {
            int ra = wr + i * 16 + lr;
            af[i]  = *(const f16x8*)((const char*)smA +
                        ((ra * 256 + ks * 64 + lkb) ^ ((ra & 7) << 4)));
            int rb = wc + i * 16 + lr;
            bfr[i] = *(const f16x8*)((const char*)smB +
                        ((rb * 256 + ks * 64 + lkb) ^ ((rb & 7) << 4)));
        }
#pragma unroll
        for (int mi = 0; mi < 4; ++mi)
#pragma unroll
            for (int ni = 0; ni < 4; ++ni)
                acc[mi][ni] = __builtin_amdgcn_mfma_f32_16x16x32_f16(
                    bfr[ni], af[mi], acc[mi][ni], 0, 0, 0);
    }

    __syncthreads();
    u16* smC = smA;
    {
        const int n4 = (l >> 4) * 4;
#pragma unroll
        for (int mi = 0; mi < 4; ++mi) {
            int m = wr + mi * 16 + lr;
#pragma unroll
            for (int ni = 0; ni < 4; ++ni) {
                int n = wc + ni * 16 + n4;
                f32x4 v = acc[mi][ni];
                ushort4 o;
                o.x = f2h(v[0]); o.y = f2h(v[1]); o.z = f2h(v[2]); o.w = f2h(v[3]);
                *(ushort4*)((char*)smC + (m * 256 + ((n * 2) ^ ((m & 7) << 4)))) = o;
            }
        }
    }
    __syncthreads();

    const int lr16 = l & 15;
    const int rg   = l >> 4;
    const int head = (bn < 512) ? (bn >> 7) : ((bn >> 7) - 4);
    const float* ap = att + head * 128 + lr16 * 8;
    float4 aa0 = *(const float4*)(ap);
    float4 aa1 = *(const float4*)(ap + 4);
    const float av[8] = {aa0.x, aa0.y, aa0.z, aa0.w, aa1.x, aa1.y, aa1.z, aa1.w};

    if (bn < 512) {
#pragma unroll
        for (int p = 0; p < 8; ++p) {
            int r = w * 32 + p * 4 + rg;
            uint4 vv = *(const uint4*)((const char*)smC +
                        (r * 256 + ((lr16 * 16) ^ ((r & 7) << 4))));
            f32x2 c0 = __builtin_convertvector(u2h2(vv.x), f32x2);
            f32x2 c1 = __builtin_convertvector(u2h2(vv.y), f32x2);
            f32x2 c2 = __builtin_convertvector(u2h2(vv.z), f32x2);
            f32x2 c3 = __builtin_convertvector(u2h2(vv.w), f32x2);
            float f[8] = {c0[0],c0[1],c1[0],c1[1],c2[0],c2[1],c3[0],c3[1]};
            float m = 0.f, d = 0.f;
#pragma unroll
            for (int k = 0; k < 8; ++k) { m = fmaxf(m, fabsf(f[k])); d += f[k] * av[k]; }
            m = rowmax16(m);
            d = rowsum16(d);
            float inv = (m > 0.f) ? (127.f / m) : 0.f;
            int q[8];
#pragma unroll
            for (int k = 0; k < 8; ++k) {
                int qi = (int)__builtin_rintf(f[k] * inv);
                q[k] = qi > 127 ? 127 : (qi < -127 ? -127 : qi);
            }
            u32 lo = (q[0]&255) | ((q[1]&255)<<8) | ((q[2]&255)<<16) | ((q[3]&255)<<24);
            u32 hi = (q[4]&255) | ((q[5]&255)<<8) | ((q[6]&255)<<16) | ((q[7]&255)<<24);
            uint2 pk; pk.x = lo; pk.y = hi;
            *(uint2*)(XLq + (size_t)(bm + r) * 512 + head * 128 + lr16 * 8) = pk;
            if (lr16 == 0)
                sclD[(bm + r) * 4 + head] =
                    (u32)f2h(m * (1.f / 127.f)) | ((u32)f2h(0.6f * d) << 16);
        }
    } else {
#pragma unroll
        for (int p = 0; p < 8; ++p) {
            int r = w * 32 + p * 4 + rg;
            uint4 vv = *(const uint4*)((const char*)smC +
                        (r * 256 + ((lr16 * 16) ^ ((r & 7) << 4))));
            f32x2 c0 = __builtin_convertvector(u2h2(vv.x), f32x2);
            f32x2 c1 = __builtin_convertvector(u2h2(vv.y), f32x2);
            f32x2 c2 = __builtin_convertvector(u2h2(vv.z), f32x2);
            f32x2 c3 = __builtin_convertvector(u2h2(vv.w), f32x2);
            float f[8] = {c0[0],c0[1],c1[0],c1[1],c2[0],c2[1],c3[0],c3[1]};
            float d = 0.f;
#pragma unroll
            for (int k = 0; k < 8; ++k) d += f[k] * av[k];
            d = rowsum16(d);
            if (lr16 == 0) Dr6[(bm + r) * 4 + head] = f2h(0.6f * d);
        }
        int r  = t >> 4;
        int cb = (t & 15) * 16;
        u16* base = XR + (bn - 512);
#pragma unroll
        for (int p = 0; p < 8; ++p) {
            int row = p * 16 + r;
            uint4 v = *(const uint4*)((const char*)smC +
                        (row * 256 + (cb ^ ((row & 7) << 4))));
            *(uint4*)(base + (size_t)(bm + row) * 512 + (cb >> 1)) = v;
        }
    }
}

// ------------- fused GATv2 attention + head-mean + bias + LN + residual -------------
// ONE WAVE PER BLOCK (64 threads), grid = NNODES: wave-granular retirement removes
// the max-of-4 per-block degree imbalance. Inner loop = proven R15/R18 structure.

__global__ __launch_bounds__(64) void k_attn(const u8*  __restrict__ XLq,
                                             const u32* __restrict__ sclD,
                                             const u16* __restrict__ Dr6,
                                             const u16* __restrict__ XR,
                                             const float* __restrict__ att,
                                             const float* __restrict__ bias,
                                             const float* __restrict__ gamma,
                                             const float* __restrict__ beta,
                                             const int* __restrict__ row,
                                             const int* __restrict__ col,
                                             const float* __restrict__ resf,
                                             const u16* __restrict__ resh,
                                             float* __restrict__ out,
                                             u16* __restrict__ out_h,
                                             int relu_flag) {
    const int n   = blockIdx.x;                    // grid = NNODES
    const int l   = threadIdx.x & 63;
    const int h   = l >> 4;
    const int e   = l & 15;

    const f16x2 M1152 = {(_Float16)(-1152.f), (_Float16)(-1152.f)};
    const u32 K64 = 0x64646464u;

    const int lane_off = h * 128 + e * 8;

    uint4 xru = *(const uint4*)(XR + (size_t)n * 512 + lane_off);
    f16x2 xr0 = u2h2(xru.x), xr1 = u2h2(xru.y), xr2 = u2h2(xru.z), xr3 = u2h2(xru.w);

    // 0.4*att in f16 pairs
    const float* ap = att + lane_off;
    float4 af0 = *(const float4*)(ap);
    float4 af1 = *(const float4*)(ap + 4);
    f16x2 at0 = {(_Float16)(0.4f*af0.x), (_Float16)(0.4f*af0.y)};
    f16x2 at1 = {(_Float16)(0.4f*af0.z), (_Float16)(0.4f*af0.w)};
    f16x2 at2 = {(_Float16)(0.4f*af1.x), (_Float16)(0.4f*af1.y)};
    f16x2 at3 = {(_Float16)(0.4f*af1.z), (_Float16)(0.4f*af1.w)};

    const float dr6n = (float)bits2h(Dr6[n * 4 + h]);   // 0.6*dot(xr_n, att_h)

    f16x2 acch[4] = {};
    float ssum = 0.f;

    const int beg = row[n], end = row[n + 1];

    for (int i = beg; i < end; i += 2) {
        int s0 = col[i];
        bool has2 = (i + 1 < end);
        int s1 = has2 ? col[i + 1] : s0;

        uint2 a0 = *(const uint2*)(XLq + (size_t)s0 * 512 + lane_off);
        uint2 a1 = *(const uint2*)(XLq + (size_t)s1 * 512 + lane_off);
        u32 sd0 = sclD[s0 * 4 + h];
        u32 sd1 = sclD[s1 * 4 + h];
        _Float16 sh0 = bits2h((u16)sd0);
        _Float16 sh1 = bits2h((u16)sd1);
        float d60 = dr6n + (float)bits2h((u16)(sd0 >> 16));
        float d61 = dr6n + (float)bits2h((u16)(sd1 >> 16));
        f16x2 s0h2 = {sh0, sh0};
        f16x2 s1h2 = {sh1, sh1};

        // magic decode int8 -> f16 (exact)
        u32 w00 = a0.x ^ 0x80808080u, w01 = a0.y ^ 0x80808080u;
        u32 w10 = a1.x ^ 0x80808080u, w11 = a1.y ^ 0x80808080u;
        f16x2 q00 = u2h2(__builtin_amdgcn_perm(K64, w00, 0x04010400u)) + M1152;
        f16x2 q01 = u2h2(__builtin_amdgcn_perm(K64, w00, 0x04030402u)) + M1152;
        f16x2 q02 = u2h2(__builtin_amdgcn_perm(K64, w01, 0x04010400u)) + M1152;
        f16x2 q03 = u2h2(__builtin_amdgcn_perm(K64, w01, 0x04030402u)) + M1152;
        f16x2 q10 = u2h2(__builtin_amdgcn_perm(K64, w10, 0x04010400u)) + M1152;
        f16x2 q11 = u2h2(__builtin_amdgcn_perm(K64, w10, 0x04030402u)) + M1152;
        f16x2 q12 = u2h2(__builtin_amdgcn_perm(K64, w11, 0x04010400u)) + M1152;
        f16x2 q13 = u2h2(__builtin_amdgcn_perm(K64, w11, 0x04030402u)) + M1152;

        float e0, e1;
        {
            f16x2 v0 = q00 * s0h2 + xr0, v1 = q01 * s0h2 + xr1;
            f16x2 v2 = q02 * s0h2 + xr2, v3 = q03 * s0h2 + xr3;
            e0 = __builtin_amdgcn_fdot2(habs2(v0), at0, 0.f, false);
            e0 = __builtin_amdgcn_fdot2(habs2(v1), at1, e0, false);
            e0 = __builtin_amdgcn_fdot2(habs2(v2), at2, e0, false);
            e0 = __builtin_amdgcn_fdot2(habs2(v3), at3, e0, false);
        }
        {
            f16x2 v0 = q10 * s1h2 + xr0, v1 = q11 * s1h2 + xr1;
            f16x2 v2 = q12 * s1h2 + xr2, v3 = q13 * s1h2 + xr3;
            e1 = __builtin_amdgcn_fdot2(habs2(v0), at0, 0.f, false);
            e1 = __builtin_amdgcn_fdot2(habs2(v1), at1, e1, false);
            e1 = __builtin_amdgcn_fdot2(habs2(v2), at2, e1, false);
            e1 = __builtin_amdgcn_fdot2(habs2(v3), at3, e1, false);
        }

        // 16-lane row reduce via DPP (pure VALU), interleaved for ILP
        e0 += DPP_ROR(e0, 0x121); e1 += DPP_ROR(e1, 0x121);
        e0 += DPP_ROR(e0, 0x122); e1 += DPP_ROR(e1, 0x122);
        e0 += DPP_ROR(e0, 0x124); e1 += DPP_ROR(e1, 0x124);
        e0 += DPP_ROR(e0, 0x128); e1 += DPP_ROR(e1, 0x128);

        float p0 = __expf(e0 + d60);
        float p1 = has2 ? __expf(e1 + d61) : 0.f;
        ssum += p0 + p1;

        _Float16 ph0s = (_Float16)(p0 * (float)sh0);
        _Float16 ph1s = (_Float16)(p1 * (float)sh1);
        f16x2 ph0 = {ph0s, ph0s};
        f16x2 ph1 = {ph1s, ph1s};
        acch[0] = acch[0] + ph0 * q00 + ph1 * q10;
        acch[1] = acch[1] + ph0 * q01 + ph1 * q11;
        acch[2] = acch[2] + ph0 * q02 + ph1 * q12;
        acch[3] = acch[3] + ph0 * q03 + ph1 * q13;
    }

    float acc[8];
    {
        f32x2 c;
        c = __builtin_convertvector(acch[0], f32x2); acc[0] = c[0]; acc[1] = c[1];
        c = __builtin_convertvector(acch[1], f32x2); acc[2] = c[0]; acc[3] = c[1];
        c = __builtin_convertvector(acch[2], f32x2); acc[4] = c[0]; acc[5] = c[1];
        c = __builtin_convertvector(acch[3], f32x2); acc[6] = c[0]; acc[7] = c[1];
    }
    float inv = 1.f / (ssum + 1e-16f);
#pragma unroll
    for (int jj = 0; jj < 8; ++jj) acc[jj] *= inv;
#pragma unroll
    for (int jj = 0; jj < 8; ++jj) acc[jj] += __shfl_xor(acc[jj], 16, 64);
#pragma unroll
    for (int jj = 0; jj < 8; ++jj) acc[jj] += __shfl_xor(acc[jj], 32, 64);

    if (h == 0) {
        const int dd = e * 8;
        float4 b40 = *(const float4*)(bias + dd);
        float4 b41 = *(const float4*)(bias + dd + 4);
        float y[8];
        y[0] = acc[0]*0.25f + b40.x; y[1] = acc[1]*0.25f + b40.y;
        y[2] = acc[2]*0.25f + b40.z; y[3] = acc[3]*0.25f + b40.w;
        y[4] = acc[4]*0.25f + b41.x; y[5] = acc[5]*0.25f + b41.y;
        y[6] = acc[6]*0.25f + b41.z; y[7] = acc[7]*0.25f + b41.w;

        float s1 = 0.f, s2 = 0.f;
#pragma unroll
        for (int jj = 0; jj < 8; ++jj) { s1 += y[jj]; s2 += y[jj]*y[jj]; }
#pragma unroll
        for (int m = 1; m < 16; m <<= 1) {
            s1 += __shfl_xor(s1, m, 64);
            s2 += __shfl_xor(s2, m, 64);
        }
        float mu = s1 * (1.f / 128.f);
        float var = s2 * (1.f / 128.f) - mu * mu;
        float rstd = rsqrtf(var + LN_EPS);

        float4 g40 = *(const float4*)(gamma + dd);
        float4 g41 = *(const float4*)(gamma + dd + 4);
        float4 e40 = *(const float4*)(beta + dd);
        float4 e41 = *(const float4*)(beta + dd + 4);
        float g[8] = {g40.x,g40.y,g40.z,g40.w,g41.x,g41.y,g41.z,g41.w};
        float be[8] = {e40.x,e40.y,e40.z,e40.w,e41.x,e41.y,e41.z,e41.w};
        float r[8];
        if (resf) {
            float4 r40 = *(const float4*)(resf + (size_t)n * 128 + dd);
            float4 r41 = *(const float4*)(resf + (size_t)n * 128 + dd + 4);
            r[0]=r40.x; r[1]=r40.y; r[2]=r40.z; r[3]=r40.w;
            r[4]=r41.x; r[5]=r41.y; r[6]=r41.z; r[7]=r41.w;
        } else {
            uint4 rh = *(const uint4*)(resh + (size_t)n * 128 + dd);
            f32x2 c;
            c = __builtin_convertvector(u2h2(rh.x), f32x2); r[0]=c[0]; r[1]=c[1];
            c = __builtin_convertvector(u2h2(rh.y), f32x2); r[2]=c[0]; r[3]=c[1];
            c = __builtin_convertvector(u2h2(rh.z), f32x2); r[4]=c[0]; r[5]=c[1];
            c = __builtin_convertvector(u2h2(rh.w), f32x2); r[6]=c[0]; r[7]=c[1];
        }
#pragma unroll
        for (int jj = 0; jj < 8; ++jj) {
            y[jj] = (y[jj] - mu) * rstd * g[jj] + be[jj] + r[jj];
            if (relu_flag) y[jj] = fmaxf(y[jj], 0.f);
        }
        if (out) {
            float4 o0 = {y[0],y[1],y[2],y[3]};
            float4 o1 = {y[4],y[5],y[6],y[7]};
            *(float4*)(out + (size_t)n * 128 + dd)     = o0;
            *(float4*)(out + (size_t)n * 128 + dd + 4) = o1;
        }
        if (out_h) {
            ushort4 oh0, oh1;
            oh0.x = f2h(y[0]); oh0.y = f2h(y[1]); oh0.z = f2h(y[2]); oh0.w = f2h(y[3]);
            oh1.x = f2h(y[4]); oh1.y = f2h(y[5]); oh1.z = f2h(y[6]); oh1.w = f2h(y[7]);
            *(ushort4*)(out_h + (size_t)n * 128 + dd)     = oh0;
            *(ushort4*)(out_h + (size_t)n * 128 + dd + 4) = oh1;
        }
    }
}

// ---------------- launch ----------------

extern "C" void kernel_launch(void* const* d_in, const int* in_sizes, int n_in,
                              void* d_out, int out_size, void* d_ws, size_t ws_size,
                              hipStream_t stream) {
    const float* x    = (const float*)d_in[0];
    const int*   src  = (const int*)d_in[1];
    const int*   dst  = (const int*)d_in[2];
    const float* Wl1  = (const float*)d_in[3];
    const float* Wr1  = (const float*)d_in[4];
    const float* att1 = (const float*)d_in[5];
    const float* b1   = (const float*)d_in[6];
    const float* g1   = (const float*)d_in[7];
    const float* be1  = (const float*)d_in[8];
    const float* Wl2  = (const float*)d_in[9];
    const float* Wr2  = (const float*)d_in[10];
    const float* att2 = (const float*)d_in[11];
    const float* b2   = (const float*)d_in[12];
    const float* g2   = (const float*)d_in[13];
    const float* be2  = (const float*)d_in[14];
    float* out = (float*)d_out;

    char* ws = (char*)d_ws;
    size_t off = 0;
    u8*    xlq  = (u8*)(ws + off);    off += (size_t)MPAD * 512;          // int8 XL
    u32*   scld = (u32*)(ws + off);   off += (size_t)MPAD * 4 * 4;        // packed scale+Dl6
    u16*   dr6  = (u16*)(ws + off);   off += (size_t)MPAD * 4 * 2;        // Dr6 f16
    u16*   xrb  = (u16*)(ws + off);   off += (size_t)MPAD * 512 * 2;      // f16 XR
    u16*   xb   = (u16*)(ws + off);   off += (size_t)MPAD * 128 * 2;      // f16 A / residual
    u16*   Bt1  = (u16*)(ws + off);   off += (size_t)1024 * 128 * 2;
    u16*   Bt2  = (u16*)(ws + off);   off += (size_t)1024 * 128 * 2;
    int*   deg  = (int*)(ws + off);   off += (size_t)NNODES * 4;
    int*   rowp = (int*)(ws + off);   off += (size_t)(NNODES + 1) * 4;
    int*   cur  = (int*)(ws + off);   off += (size_t)NNODES * 4;
    int*   col  = (int*)(ws + off);   off += (size_t)ETOT * 4;

    k_prep<<<256, 256, 0, stream>>>(x, xb, Wl1, Wr1, Bt1, Wl2, Wr2, Bt2, deg);
    k_hist<<<(NEDGES + 255) / 256, 256, 0, stream>>>(dst, deg);
    k_scan<<<1, 1024, 0, stream>>>(deg, rowp, cur);
    k_scatter<<<(ETOT + 255) / 256, 256, 0, stream>>>(src, dst, col, cur);

    // layer 1: residual = x (f32); output only f16 into xb (becomes layer-2 input+residual)
    k_gemm_f16<<<MPAD / 128 * 8, 256, 0, stream>>>(xb, Bt1, att1, xlq, scld, dr6, xrb);
    k_attn<<<NNODES, 64, 0, stream>>>(xlq, scld, dr6, xrb, att1, b1, g1, be1,
                                      rowp, col, x, (const u16*)nullptr,
                                      (float*)nullptr, xb, 1);
    // layer 2: residual = xb (f16); output f32 to d_out
    k_gemm_f16<<<MPAD / 128 * 8, 256, 0, stream>>>(xb, Bt2, att2, xlq, scld, dr6, xrb);
    k_attn<<<NNODES, 64, 0, stream>>>(xlq, scld, dr6, xrb, att2, b2, g2, be2,
                                      rowp, col, (const float*)nullptr, xb,
                                      out, (u16*)nullptr, 0);
}